// Round 2
// baseline (2505.602 us; speedup 1.0000x reference)
//
#include <hip/hip_runtime.h>
#include <stdint.h>

typedef uint16_t u16;
typedef __attribute__((ext_vector_type(8))) __bf16 bfrag8;
typedef __attribute__((ext_vector_type(4))) float f32x4;

#define DEV __device__ __forceinline__

DEV float bf2f(uint32_t lo16) { return __uint_as_float(lo16 << 16); }
DEV u16 f2bf(float f) {
  uint32_t u = __float_as_uint(f);
  u += 0x7fffu + ((u >> 16) & 1u);   // RNE
  return (u16)(u >> 16);
}
DEV float sigmoidf_(float x) { return 1.f / (1.f + __expf(-x)); }

// block-wide (256-thread) sum; caller must call uniformly
DEV float blk_sum(float v, float* sred, int tid) {
#pragma unroll
  for (int m = 32; m >= 1; m >>= 1) v += __shfl_xor(v, m);
  __syncthreads();                       // protect previous read of sred
  if ((tid & 63) == 0) sred[tid >> 6] = v;
  __syncthreads();
  return sred[0] + sred[1] + sred[2] + sred[3];
}

// -------------------- weight transpose fp32[K,N] -> bf16[N,K] --------------------
__global__ __launch_bounds__(256) void transpose_w(const float* __restrict__ W,
                                                   u16* __restrict__ WT, int Kd_, int Nd_) {
  __shared__ float tile[32][33];
  int tx = threadIdx.x, ty = threadIdx.y;
  int n0 = blockIdx.x * 32, k0 = blockIdx.y * 32;
#pragma unroll
  for (int i = ty; i < 32; i += 8) tile[i][tx] = W[(size_t)(k0 + i) * Nd_ + n0 + tx];
  __syncthreads();
#pragma unroll
  for (int i = ty; i < 32; i += 8) WT[(size_t)(n0 + i) * Kd_ + k0 + tx] = f2bf(tile[tx][i]);
}

// -------------------- LN1 + RMSnorm + (h@Wa, h@Wb -> g, beta) --------------------
__global__ __launch_bounds__(256) void k1_kernel(
    const float* __restrict__ x, const float* __restrict__ ln1g, const float* __restrict__ ln1b,
    const float* __restrict__ rmsw, const float* __restrict__ Wa, const float* __restrict__ Wb,
    const float* __restrict__ dtb, const float* __restrict__ Alog,
    u16* __restrict__ hbf, float* __restrict__ g, float* __restrict__ beta) {
  __shared__ float sred[4];
  int row = blockIdx.x, tid = threadIdx.x;
  const float4 xv = ((const float4*)(x + (size_t)row * 1024))[tid];
  float ts  = blk_sum(xv.x + xv.y + xv.z + xv.w, sred, tid);
  float ts2 = blk_sum(xv.x * xv.x + xv.y * xv.y + xv.z * xv.z + xv.w * xv.w, sred, tid);
  float mean = ts * (1.f / 1024.f);
  float var  = ts2 * (1.f / 1024.f) - mean * mean;
  float inv  = rsqrtf(var + 1e-5f);
  int c = tid * 4;
  float l0 = (xv.x - mean) * inv * ln1g[c + 0] + ln1b[c + 0];
  float l1 = (xv.y - mean) * inv * ln1g[c + 1] + ln1b[c + 1];
  float l2 = (xv.z - mean) * inv * ln1g[c + 2] + ln1b[c + 2];
  float l3 = (xv.w - mean) * inv * ln1g[c + 3] + ln1b[c + 3];
  float ssq = blk_sum(l0 * l0 + l1 * l1 + l2 * l2 + l3 * l3, sred, tid);
  float rinv = rsqrtf(ssq * (1.f / 1024.f) + 1e-6f);
  float h0 = l0 * rinv * rmsw[c + 0];
  float h1 = l1 * rinv * rmsw[c + 1];
  float h2 = l2 * rinv * rmsw[c + 2];
  float h3 = l3 * rinv * rmsw[c + 3];
  uint2 pk;
  pk.x = (uint32_t)f2bf(h0) | ((uint32_t)f2bf(h1) << 16);
  pk.y = (uint32_t)f2bf(h2) | ((uint32_t)f2bf(h3) << 16);
  *(uint2*)(hbf + (size_t)row * 1024 + c) = pk;
  float hv[4] = {h0, h1, h2, h3};
  float pa[4] = {0, 0, 0, 0}, pb[4] = {0, 0, 0, 0};
#pragma unroll
  for (int e = 0; e < 4; e++) {
    const float* wa = Wa + (size_t)(c + e) * 4;
    const float* wb = Wb + (size_t)(c + e) * 4;
#pragma unroll
    for (int p = 0; p < 4; p++) {
      pa[p] = fmaf(hv[e], wa[p], pa[p]);
      pb[p] = fmaf(hv[e], wb[p], pb[p]);
    }
  }
  float ra[4], rb[4];
  for (int p = 0; p < 4; p++) ra[p] = blk_sum(pa[p], sred, tid);
  for (int p = 0; p < 4; p++) rb[p] = blk_sum(pb[p], sred, tid);
  if (tid < 4) {
    float z = ra[tid] + dtb[tid];
    float sp = fmaxf(z, 0.f) + log1pf(expf(-fabsf(z)));   // stable softplus
    g[(size_t)row * 4 + tid]    = -expf(Alog[tid]) * sp;
    beta[(size_t)row * 4 + tid] = 1.f / (1.f + expf(-rb[tid]));
  }
}

// -------------------- bf16 MFMA GEMM: C[M,N] = A[M,K] * Bt[N,K]^T --------------------
// MODE 0: outh = bf16(acc); MODE 1: outf = acc + res; MODE 2: outf = gelu(acc+bias) + res
template <int MODE>
__global__ __launch_bounds__(256) void gemm_bt(
    const u16* __restrict__ A, const u16* __restrict__ Bt, int M, int N, int K,
    float* __restrict__ outf, u16* __restrict__ outh,
    const float* __restrict__ res, const float* __restrict__ bias) {
  __shared__ u16 As[128 * 64];
  __shared__ u16 Bs[128 * 64];
  const int tid = threadIdx.x;
  const int lane = tid & 63;
  const int wv = tid >> 6;
  const int quad = lane >> 4;
  const int l16 = lane & 15;
  const int waveM = (wv & 1) * 64;
  const int waveN = (wv >> 1) * 64;
  const size_t arow0 = (size_t)blockIdx.y * 128;
  const size_t brow0 = (size_t)blockIdx.x * 128;
  const int srow = tid >> 3;          // 0..31
  const int soff = (tid & 7) * 8;     // 16B chunks within a 64-elem row
  f32x4 acc[4][4];
#pragma unroll
  for (int i = 0; i < 4; i++)
#pragma unroll
    for (int j = 0; j < 4; j++) acc[i][j] = (f32x4){0.f, 0.f, 0.f, 0.f};

  for (int k0 = 0; k0 < K; k0 += 64) {
    __syncthreads();
#pragma unroll
    for (int i = 0; i < 4; i++) {
      int r = i * 32 + srow;
      *(int4*)(As + r * 64 + soff) = *(const int4*)(A + (arow0 + r) * K + k0 + soff);
      *(int4*)(Bs + r * 64 + soff) = *(const int4*)(Bt + (brow0 + r) * K + k0 + soff);
    }
    __syncthreads();
#pragma unroll
    for (int kk = 0; kk < 2; kk++) {
      bfrag8 af[4], bfr[4];
#pragma unroll
      for (int i = 0; i < 4; i++) {
        af[i]  = *(const bfrag8*)(As + (waveM + i * 16 + l16) * 64 + kk * 32 + quad * 8);
        bfr[i] = *(const bfrag8*)(Bs + (waveN + i * 16 + l16) * 64 + kk * 32 + quad * 8);
      }
#pragma unroll
      for (int i = 0; i < 4; i++)
#pragma unroll
        for (int j = 0; j < 4; j++)
          acc[i][j] = __builtin_amdgcn_mfma_f32_16x16x32_bf16(af[i], bfr[j], acc[i][j], 0, 0, 0);
    }
  }
#pragma unroll
  for (int i = 0; i < 4; i++) {
    int r0 = (int)arow0 + waveM + i * 16 + quad * 4;
#pragma unroll
    for (int j = 0; j < 4; j++) {
      int cN = (int)brow0 + waveN + j * 16 + l16;
#pragma unroll
      for (int r = 0; r < 4; r++) {
        size_t idx = (size_t)(r0 + r) * N + cN;
        float vacc = acc[i][j][r];
        if (MODE == 0) {
          outh[idx] = f2bf(vacc);
        } else if (MODE == 1) {
          outf[idx] = vacc + res[idx];
        } else {
          float z = vacc + bias[cN];
          float ge = 0.5f * z * (1.f + erff(z * 0.70710678118654752f));
          outf[idx] = ge + res[idx];
        }
      }
    }
  }
}

// -------------------- causal conv(4) + SiLU + L2norm for q,k (bf16 out) --------------------
// qkv layout: [row, 4096] = [q(1024) | k(1024) | v(2048)]
__global__ __launch_bounds__(256) void conv_qk_kernel(
    const u16* __restrict__ qkv, const float* __restrict__ cwq, const float* __restrict__ cwk,
    u16* __restrict__ qf, u16* __restrict__ kf) {
  __shared__ float sred[4];
  int row = blockIdx.x, tid = threadIdx.x;
  int t = row & 2047;
  int isK = (blockIdx.y >= 4);
  int hh = blockIdx.y & 3;
  int c = hh * 256 + tid;                  // channel within the 1024-wide projection
  const float* cw = isK ? cwk : cwq;
  int col = (isK ? 1024 : 0) + c;          // column in qkv
  float acc = 0.f;
#pragma unroll
  for (int i = 0; i < 4; i++) {
    int tt = t - 3 + i;
    if (tt >= 0) acc = fmaf(cw[c * 4 + i], bf2f(qkv[(size_t)(row - 3 + i) * 4096 + col]), acc);
  }
  float y = acc * sigmoidf_(acc);          // silu
  float ssq = blk_sum(y * y, sred, tid);   // l2 over the head's 256 dims
  float r = rsqrtf(ssq + 1e-6f);
  float outv = y * r * (isK ? 1.f : 0.0625f);   // q gets Kd^-0.5
  (isK ? kf : qf)[(size_t)row * 1024 + c] = f2bf(outv);
}

// -------------------- causal conv(4) + SiLU for v (bf16 out) --------------------
__global__ __launch_bounds__(256) void conv_v_kernel(
    const u16* __restrict__ qkv, const float* __restrict__ cwv, u16* __restrict__ vf) {
  int row = blockIdx.x, tid = threadIdx.x;
  int t = row & 2047;
  int c0 = blockIdx.y * 1024 + tid * 4;    // channel in [0,2048)
  float a0 = 0, a1 = 0, a2 = 0, a3 = 0;
#pragma unroll
  for (int i = 0; i < 4; i++) {
    int tt = t - 3 + i;
    if (tt >= 0) {
      uint2 raw = *(const uint2*)(qkv + (size_t)(row - 3 + i) * 4096 + 2048 + c0);
      a0 = fmaf(cwv[(c0 + 0) * 4 + i], bf2f(raw.x & 0xffffu), a0);
      a1 = fmaf(cwv[(c0 + 1) * 4 + i], bf2f(raw.x >> 16), a1);
      a2 = fmaf(cwv[(c0 + 2) * 4 + i], bf2f(raw.y & 0xffffu), a2);
      a3 = fmaf(cwv[(c0 + 3) * 4 + i], bf2f(raw.y >> 16), a3);
    }
  }
  a0 = a0 * sigmoidf_(a0);
  a1 = a1 * sigmoidf_(a1);
  a2 = a2 * sigmoidf_(a2);
  a3 = a3 * sigmoidf_(a3);
  uint2 pk;
  pk.x = (uint32_t)f2bf(a0) | ((uint32_t)f2bf(a1) << 16);
  pk.y = (uint32_t)f2bf(a2) | ((uint32_t)f2bf(a3) << 16);
  *(uint2*)(vf + (size_t)row * 2048 + c0) = pk;
}

// -------------------- gated delta rule: column-parallel sequential scan --------------------
// 8192 independent (b,h,v) columns; 4 columns per wave; lane l owns k = l + 64*j (j=0..3).
__global__ __launch_bounds__(256) void scan_kernel(
    const u16* __restrict__ q, const u16* __restrict__ k, const u16* __restrict__ v,
    const float* __restrict__ g, const float* __restrict__ beta, u16* __restrict__ o) {
  int tid = threadIdx.x;
  int lane = tid & 63;
  int wv = tid >> 6;
  int wg = blockIdx.x * 4 + wv;   // 0..2047
  int c0 = wg * 4;
  int b = c0 >> 11;
  int hh = (c0 >> 9) & 3;
  int v0 = c0 & 511;
  float S[4][4];                  // S[col][j]
#pragma unroll
  for (int cc = 0; cc < 4; cc++)
#pragma unroll
    for (int j = 0; j < 4; j++) S[cc][j] = 0.f;
  const size_t rowb = (size_t)b * 2048;
  for (int t = 0; t < 2048; t++) {
    size_t row = rowb + t;
    float gt = g[row * 4 + hh];
    float bt = beta[row * 4 + hh];
    float eg = __expf(gt);
    const u16* kr = k + row * 1024 + hh * 256 + lane;
    const u16* qr = q + row * 1024 + hh * 256 + lane;
    float kt0 = bf2f(kr[0]), kt1 = bf2f(kr[64]), kt2 = bf2f(kr[128]), kt3 = bf2f(kr[192]);
    float qt0 = bf2f(qr[0]), qt1 = bf2f(qr[64]), qt2 = bf2f(qr[128]), qt3 = bf2f(qr[192]);
    float vt = bf2f(v[row * 2048 + hh * 512 + v0 + (lane & 3)]);
    float p[4];
#pragma unroll
    for (int cc = 0; cc < 4; cc++) {
      S[cc][0] *= eg; S[cc][1] *= eg; S[cc][2] *= eg; S[cc][3] *= eg;
      p[cc] = fmaf(kt0, S[cc][0], fmaf(kt1, S[cc][1], fmaf(kt2, S[cc][2], kt3 * S[cc][3])));
    }
    // fold 4 column-partials into lane%4, then butterfly across quads
    float t0 = __shfl_xor(p[0], 1), t1 = __shfl_xor(p[1], 1);
    float fa = (lane & 1) ? (p[1] + t1) : (p[0] + t0);
    float t2 = __shfl_xor(p[2], 1), t3 = __shfl_xor(p[3], 1);
    float fb = (lane & 1) ? (p[3] + t3) : (p[2] + t2);
    float ta = __shfl_xor(fa, 2), tb = __shfl_xor(fb, 2);
    float r = (lane & 2) ? (fb + tb) : (fa + ta);
    r += __shfl_xor(r, 4); r += __shfl_xor(r, 8); r += __shfl_xor(r, 16); r += __shfl_xor(r, 32);
    float dself = (vt - r) * bt;      // delta for column lane&3
    float dv[4];
    dv[0] = __shfl(dself, 0); dv[1] = __shfl(dself, 1);
    dv[2] = __shfl(dself, 2); dv[3] = __shfl(dself, 3);
    float op[4];
#pragma unroll
    for (int cc = 0; cc < 4; cc++) {
      S[cc][0] = fmaf(kt0, dv[cc], S[cc][0]);
      S[cc][1] = fmaf(kt1, dv[cc], S[cc][1]);
      S[cc][2] = fmaf(kt2, dv[cc], S[cc][2]);
      S[cc][3] = fmaf(kt3, dv[cc], S[cc][3]);
      op[cc] = fmaf(qt0, S[cc][0], fmaf(qt1, S[cc][1], fmaf(qt2, S[cc][2], qt3 * S[cc][3])));
    }
    float u0 = __shfl_xor(op[0], 1), u1 = __shfl_xor(op[1], 1);
    float ga = (lane & 1) ? (op[1] + u1) : (op[0] + u0);
    float u2 = __shfl_xor(op[2], 1), u3 = __shfl_xor(op[3], 1);
    float gb = (lane & 1) ? (op[3] + u3) : (op[2] + u2);
    float ua = __shfl_xor(ga, 2), ub = __shfl_xor(gb, 2);
    float ro = (lane & 2) ? (gb + ub) : (ga + ua);
    ro += __shfl_xor(ro, 4); ro += __shfl_xor(ro, 8); ro += __shfl_xor(ro, 16); ro += __shfl_xor(ro, 32);
    if (lane < 4) o[row * 2048 + hh * 512 + v0 + lane] = f2bf(ro);
  }
}

// -------------------- gated RMS-norm of o: bf16 out --------------------
__global__ __launch_bounds__(256) void onorm_kernel(
    const u16* __restrict__ o, const u16* __restrict__ gate,
    const float* __restrict__ onw, u16* __restrict__ ofin) {
  __shared__ float sred[4];
  int row = blockIdx.x, hh = blockIdx.y, tid = threadIdx.x;
  size_t base = (size_t)row * 2048 + hh * 512;
  uint32_t oraw = *(const uint32_t*)(o + base + tid * 2);
  float o0 = bf2f(oraw & 0xffffu), o1 = bf2f(oraw >> 16);
  float ssq = blk_sum(o0 * o0 + o1 * o1, sred, tid);
  float rinv = rsqrtf(ssq * (1.f / 512.f) + 1e-6f);
  uint32_t graw = *(const uint32_t*)(gate + base + tid * 2);
  float g0 = bf2f(graw & 0xffffu), g1 = bf2f(graw >> 16);
  float r0 = o0 * rinv * onw[tid * 2 + 0] * (g0 * sigmoidf_(g0));
  float r1 = o1 * rinv * onw[tid * 2 + 1] * (g1 * sigmoidf_(g1));
  uint32_t pk = (uint32_t)f2bf(r0) | ((uint32_t)f2bf(r1) << 16);
  *(uint32_t*)(ofin + base + tid * 2) = pk;
}

// -------------------- LN2 --------------------
__global__ __launch_bounds__(256) void ln2_kernel(
    const float* __restrict__ x1, const float* __restrict__ g2, const float* __restrict__ b2,
    u16* __restrict__ h2) {
  __shared__ float sred[4];
  int row = blockIdx.x, tid = threadIdx.x;
  const float4 xv = ((const float4*)(x1 + (size_t)row * 1024))[tid];
  float ts  = blk_sum(xv.x + xv.y + xv.z + xv.w, sred, tid);
  float ts2 = blk_sum(xv.x * xv.x + xv.y * xv.y + xv.z * xv.z + xv.w * xv.w, sred, tid);
  float mean = ts * (1.f / 1024.f);
  float inv = rsqrtf(ts2 * (1.f / 1024.f) - mean * mean + 1e-5f);
  int c = tid * 4;
  float h0 = (xv.x - mean) * inv * g2[c + 0] + b2[c + 0];
  float h1 = (xv.y - mean) * inv * g2[c + 1] + b2[c + 1];
  float h2v = (xv.z - mean) * inv * g2[c + 2] + b2[c + 2];
  float h3 = (xv.w - mean) * inv * g2[c + 3] + b2[c + 3];
  uint2 pk;
  pk.x = (uint32_t)f2bf(h0) | ((uint32_t)f2bf(h1) << 16);
  pk.y = (uint32_t)f2bf(h2v) | ((uint32_t)f2bf(h3) << 16);
  *(uint2*)(h2 + (size_t)row * 1024 + c) = pk;
}

// ==================== launch ====================
// Workspace layout (bytes), total ~162.3 MB with liveness overlap:
//  [0,64M)    qkv_proj bf16 8192x4096   (gemm_qkv -> convs)
//  [0,32M)    obuf bf16 8192x2048       (scan -> onorm; overlays dead qkv lower half)
//  [32M,64M)  gate bf16 8192x2048       (gemm_gate -> onorm; overlays dead qkv upper half)
//  [64M,80M)  hbf bf16 8192x1024        (k1 -> gemm_gate)
//  [80M,88M)  WTqkv bf16 4096x1024
//  [88M,92M)  WgT bf16 2048x1024
//  [92M,96M)  WoT bf16 1024x2048
//  [96M,98M)  W2T bf16 1024x1024
//  [98M,114M) qf bf16 8192x1024         (conv -> scan)
//  [114M,130M)kf bf16 8192x1024         (conv -> scan)
//  [130M,162M)vf bf16 8192x2048         (conv -> scan)
//  [98M,130M) ofin bf16 8192x2048       (onorm -> gemm1; overlays dead qf/kf)
//  [130M,146M)h2bf bf16 8192x1024       (ln2 -> gemm2; overlays dead vf)
//  [162M,+)   gbuf/bbuf fp32 8192x4 each
// x1 (post-o_proj residual) lives in d_out itself.
extern "C" void kernel_launch(void* const* d_in, const int* in_sizes, int n_in,
                              void* d_out, int out_size, void* d_ws, size_t ws_size,
                              hipStream_t stream) {
  (void)in_sizes; (void)n_in; (void)out_size; (void)ws_size;
  const float* x    = (const float*)d_in[0];
  const float* ln1g = (const float*)d_in[1];
  const float* ln1b = (const float*)d_in[2];
  const float* ln2g = (const float*)d_in[3];
  const float* ln2b = (const float*)d_in[4];
  const float* rmsw = (const float*)d_in[5];
  const float* Wq   = (const float*)d_in[6];
  const float* Wk   = (const float*)d_in[7];
  const float* Wv   = (const float*)d_in[8];
  const float* cwq  = (const float*)d_in[9];
  const float* cwk  = (const float*)d_in[10];
  const float* cwv  = (const float*)d_in[11];
  const float* Wa   = (const float*)d_in[12];
  const float* dtb  = (const float*)d_in[13];
  const float* Alog = (const float*)d_in[14];
  const float* Wb   = (const float*)d_in[15];
  const float* Wg   = (const float*)d_in[16];
  const float* onw  = (const float*)d_in[17];
  const float* Wo   = (const float*)d_in[18];
  const float* W2   = (const float*)d_in[19];
  const float* b2   = (const float*)d_in[20];

  uint8_t* ws = (uint8_t*)d_ws;
  const size_t MB = 1024ull * 1024;
  u16*   qkvp  = (u16*)(ws);               // 64MB
  u16*   obuf  = (u16*)(ws);               // 32MB (overlay)
  u16*   gate  = (u16*)(ws + 32 * MB);     // 32MB (overlay)
  u16*   hbf   = (u16*)(ws + 64 * MB);     // 16MB
  u16*   WTqkv = (u16*)(ws + 80 * MB);     // 8MB
  u16*   WgT   = (u16*)(ws + 88 * MB);     // 4MB
  u16*   WoT   = (u16*)(ws + 92 * MB);     // 4MB
  u16*   W2T   = (u16*)(ws + 96 * MB);     // 2MB
  u16*   qf    = (u16*)(ws + 98 * MB);     // 16MB
  u16*   kf    = (u16*)(ws + 114 * MB);    // 16MB
  u16*   vf    = (u16*)(ws + 130 * MB);    // 32MB
  u16*   ofin  = (u16*)(ws + 98 * MB);     // 32MB (overlay qf/kf)
  u16*   h2bf  = (u16*)(ws + 130 * MB);    // 16MB (overlay vf)
  float* gbuf  = (float*)(ws + 162 * MB);  // 128KB
  float* bbuf  = (float*)(ws + 162 * MB + 131072);
  float* x1    = (float*)d_out;            // residual stage lives in d_out
  float* outp  = (float*)d_out;

  dim3 tb(32, 8);
  transpose_w<<<dim3(32, 32), tb, 0, stream>>>(Wq, WTqkv,               1024, 1024);
  transpose_w<<<dim3(32, 32), tb, 0, stream>>>(Wk, WTqkv + 1024 * 1024, 1024, 1024);
  transpose_w<<<dim3(64, 32), tb, 0, stream>>>(Wv, WTqkv + 2048 * 1024, 1024, 2048);
  transpose_w<<<dim3(64, 32), tb, 0, stream>>>(Wg, WgT,                 1024, 2048);
  transpose_w<<<dim3(32, 64), tb, 0, stream>>>(Wo, WoT,                 2048, 1024);
  transpose_w<<<dim3(32, 32), tb, 0, stream>>>(W2, W2T,                 1024, 1024);

  k1_kernel<<<8192, 256, 0, stream>>>(x, ln1g, ln1b, rmsw, Wa, Wb, dtb, Alog, hbf, gbuf, bbuf);
  gemm_bt<0><<<dim3(32, 64), 256, 0, stream>>>(hbf, WTqkv, 8192, 4096, 1024, nullptr, qkvp, nullptr, nullptr);
  conv_qk_kernel<<<dim3(8192, 8), 256, 0, stream>>>(qkvp, cwq, cwk, qf, kf);
  conv_v_kernel<<<dim3(8192, 2), 256, 0, stream>>>(qkvp, cwv, vf);
  scan_kernel<<<512, 256, 0, stream>>>(qf, kf, vf, gbuf, bbuf, obuf);
  gemm_bt<0><<<dim3(16, 64), 256, 0, stream>>>(hbf, WgT, 8192, 2048, 1024, nullptr, gate, nullptr, nullptr);
  onorm_kernel<<<dim3(8192, 4), 256, 0, stream>>>(obuf, gate, onw, ofin);
  gemm_bt<1><<<dim3(8, 64), 256, 0, stream>>>(ofin, WoT, 8192, 1024, 2048, x1, nullptr, x, nullptr);
  ln2_kernel<<<8192, 256, 0, stream>>>(x1, ln2g, ln2b, h2bf);
  gemm_bt<2><<<dim3(8, 64), 256, 0, stream>>>(h2bf, W2T, 8192, 1024, 1024, outp, nullptr, x1, b2);
}

// Round 3
// 2286.218 us; speedup vs baseline: 1.0960x; 1.0960x over previous
//
#include <hip/hip_runtime.h>
#include <stdint.h>

typedef uint16_t u16;
typedef __attribute__((ext_vector_type(8))) __bf16 bfrag8;
typedef __attribute__((ext_vector_type(4))) float f32x4;

#define DEV __device__ __forceinline__

DEV float bf2f(uint32_t lo16) { return __uint_as_float(lo16 << 16); }
DEV float bflo(uint32_t u) { return __uint_as_float(u << 16); }
DEV float bfhi(uint32_t u) { return __uint_as_float(u & 0xffff0000u); }
DEV u16 f2bf(float f) {
  uint32_t u = __float_as_uint(f);
  u += 0x7fffu + ((u >> 16) & 1u);   // RNE
  return (u16)(u >> 16);
}
DEV float sigmoidf_(float x) { return 1.f / (1.f + __expf(-x)); }

// block-wide (256-thread) sum; caller must call uniformly
DEV float blk_sum(float v, float* sred, int tid) {
#pragma unroll
  for (int m = 32; m >= 1; m >>= 1) v += __shfl_xor(v, m);
  __syncthreads();                       // protect previous read of sred
  if ((tid & 63) == 0) sred[tid >> 6] = v;
  __syncthreads();
  return sred[0] + sred[1] + sred[2] + sred[3];
}

// -------------------- weight transpose fp32[K,N] -> bf16[N,K] --------------------
__global__ __launch_bounds__(256) void transpose_w(const float* __restrict__ W,
                                                   u16* __restrict__ WT, int Kd_, int Nd_) {
  __shared__ float tile[32][33];
  int tx = threadIdx.x, ty = threadIdx.y;
  int n0 = blockIdx.x * 32, k0 = blockIdx.y * 32;
#pragma unroll
  for (int i = ty; i < 32; i += 8) tile[i][tx] = W[(size_t)(k0 + i) * Nd_ + n0 + tx];
  __syncthreads();
#pragma unroll
  for (int i = ty; i < 32; i += 8) WT[(size_t)(n0 + i) * Kd_ + k0 + tx] = f2bf(tile[tx][i]);
}

// -------------------- LN1 + RMSnorm + (h@Wa, h@Wb -> {exp(g), beta}) --------------------
__global__ __launch_bounds__(256) void k1_kernel(
    const float* __restrict__ x, const float* __restrict__ ln1g, const float* __restrict__ ln1b,
    const float* __restrict__ rmsw, const float* __restrict__ Wa, const float* __restrict__ Wb,
    const float* __restrict__ dtb, const float* __restrict__ Alog,
    u16* __restrict__ hbf, float2* __restrict__ gb2) {
  __shared__ float sred[4];
  int row = blockIdx.x, tid = threadIdx.x;
  const float4 xv = ((const float4*)(x + (size_t)row * 1024))[tid];
  float ts  = blk_sum(xv.x + xv.y + xv.z + xv.w, sred, tid);
  float ts2 = blk_sum(xv.x * xv.x + xv.y * xv.y + xv.z * xv.z + xv.w * xv.w, sred, tid);
  float mean = ts * (1.f / 1024.f);
  float var  = ts2 * (1.f / 1024.f) - mean * mean;
  float inv  = rsqrtf(var + 1e-5f);
  int c = tid * 4;
  float l0 = (xv.x - mean) * inv * ln1g[c + 0] + ln1b[c + 0];
  float l1 = (xv.y - mean) * inv * ln1g[c + 1] + ln1b[c + 1];
  float l2 = (xv.z - mean) * inv * ln1g[c + 2] + ln1b[c + 2];
  float l3 = (xv.w - mean) * inv * ln1g[c + 3] + ln1b[c + 3];
  float ssq = blk_sum(l0 * l0 + l1 * l1 + l2 * l2 + l3 * l3, sred, tid);
  float rinv = rsqrtf(ssq * (1.f / 1024.f) + 1e-6f);
  float h0 = l0 * rinv * rmsw[c + 0];
  float h1 = l1 * rinv * rmsw[c + 1];
  float h2 = l2 * rinv * rmsw[c + 2];
  float h3 = l3 * rinv * rmsw[c + 3];
  uint2 pk;
  pk.x = (uint32_t)f2bf(h0) | ((uint32_t)f2bf(h1) << 16);
  pk.y = (uint32_t)f2bf(h2) | ((uint32_t)f2bf(h3) << 16);
  *(uint2*)(hbf + (size_t)row * 1024 + c) = pk;
  float hv[4] = {h0, h1, h2, h3};
  float pa[4] = {0, 0, 0, 0}, pb[4] = {0, 0, 0, 0};
#pragma unroll
  for (int e = 0; e < 4; e++) {
    const float* wa = Wa + (size_t)(c + e) * 4;
    const float* wb = Wb + (size_t)(c + e) * 4;
#pragma unroll
    for (int p = 0; p < 4; p++) {
      pa[p] = fmaf(hv[e], wa[p], pa[p]);
      pb[p] = fmaf(hv[e], wb[p], pb[p]);
    }
  }
  float ra[4], rb[4];
  for (int p = 0; p < 4; p++) ra[p] = blk_sum(pa[p], sred, tid);
  for (int p = 0; p < 4; p++) rb[p] = blk_sum(pb[p], sred, tid);
  if (tid < 4) {
    float z = ra[tid] + dtb[tid];
    float sp = fmaxf(z, 0.f) + log1pf(expf(-fabsf(z)));   // stable softplus
    float gg = -expf(Alog[tid]) * sp;
    float2 o2;
    o2.x = expf(gg);                       // scan only ever needs exp(g)
    o2.y = 1.f / (1.f + expf(-rb[tid]));
    gb2[(size_t)row * 4 + tid] = o2;
  }
}

// -------------------- bf16 MFMA GEMM: C[M,N] = A[M,K] * Bt[N,K]^T --------------------
// MODE 0: outh = bf16(acc); MODE 1: outf = acc + res; MODE 2: outf = gelu(acc+bias) + res
template <int MODE>
__global__ __launch_bounds__(256) void gemm_bt(
    const u16* __restrict__ A, const u16* __restrict__ Bt, int M, int N, int K,
    float* __restrict__ outf, u16* __restrict__ outh,
    const float* __restrict__ res, const float* __restrict__ bias) {
  __shared__ u16 As[128 * 64];
  __shared__ u16 Bs[128 * 64];
  const int tid = threadIdx.x;
  const int lane = tid & 63;
  const int wv = tid >> 6;
  const int quad = lane >> 4;
  const int l16 = lane & 15;
  const int waveM = (wv & 1) * 64;
  const int waveN = (wv >> 1) * 64;
  const size_t arow0 = (size_t)blockIdx.y * 128;
  const size_t brow0 = (size_t)blockIdx.x * 128;
  const int srow = tid >> 3;          // 0..31
  const int soff = (tid & 7) * 8;     // 16B chunks within a 64-elem row
  f32x4 acc[4][4];
#pragma unroll
  for (int i = 0; i < 4; i++)
#pragma unroll
    for (int j = 0; j < 4; j++) acc[i][j] = (f32x4){0.f, 0.f, 0.f, 0.f};

  for (int k0 = 0; k0 < K; k0 += 64) {
    __syncthreads();
#pragma unroll
    for (int i = 0; i < 4; i++) {
      int r = i * 32 + srow;
      *(int4*)(As + r * 64 + soff) = *(const int4*)(A + (arow0 + r) * K + k0 + soff);
      *(int4*)(Bs + r * 64 + soff) = *(const int4*)(Bt + (brow0 + r) * K + k0 + soff);
    }
    __syncthreads();
#pragma unroll
    for (int kk = 0; kk < 2; kk++) {
      bfrag8 af[4], bfr[4];
#pragma unroll
      for (int i = 0; i < 4; i++) {
        af[i]  = *(const bfrag8*)(As + (waveM + i * 16 + l16) * 64 + kk * 32 + quad * 8);
        bfr[i] = *(const bfrag8*)(Bs + (waveN + i * 16 + l16) * 64 + kk * 32 + quad * 8);
      }
#pragma unroll
      for (int i = 0; i < 4; i++)
#pragma unroll
        for (int j = 0; j < 4; j++)
          acc[i][j] = __builtin_amdgcn_mfma_f32_16x16x32_bf16(af[i], bfr[j], acc[i][j], 0, 0, 0);
    }
  }
#pragma unroll
  for (int i = 0; i < 4; i++) {
    int r0 = (int)arow0 + waveM + i * 16 + quad * 4;
#pragma unroll
    for (int j = 0; j < 4; j++) {
      int cN = (int)brow0 + waveN + j * 16 + l16;
#pragma unroll
      for (int r = 0; r < 4; r++) {
        size_t idx = (size_t)(r0 + r) * N + cN;
        float vacc = acc[i][j][r];
        if (MODE == 0) {
          outh[idx] = f2bf(vacc);
        } else if (MODE == 1) {
          outf[idx] = vacc + res[idx];
        } else {
          float z = vacc + bias[cN];
          float ge = 0.5f * z * (1.f + erff(z * 0.70710678118654752f));
          outf[idx] = ge + res[idx];
        }
      }
    }
  }
}

// -------------------- causal conv(4) + SiLU + L2norm for q,k (bf16 out) --------------------
// qkv layout: [row, 4096] = [q(1024) | k(1024) | v(2048)]
__global__ __launch_bounds__(256) void conv_qk_kernel(
    const u16* __restrict__ qkv, const float* __restrict__ cwq, const float* __restrict__ cwk,
    u16* __restrict__ qf, u16* __restrict__ kf) {
  __shared__ float sred[4];
  int row = blockIdx.x, tid = threadIdx.x;
  int t = row & 2047;
  int isK = (blockIdx.y >= 4);
  int hh = blockIdx.y & 3;
  int c = hh * 256 + tid;                  // channel within the 1024-wide projection
  const float* cw = isK ? cwk : cwq;
  int col = (isK ? 1024 : 0) + c;          // column in qkv
  float acc = 0.f;
#pragma unroll
  for (int i = 0; i < 4; i++) {
    int tt = t - 3 + i;
    if (tt >= 0) acc = fmaf(cw[c * 4 + i], bf2f(qkv[(size_t)(row - 3 + i) * 4096 + col]), acc);
  }
  float y = acc * sigmoidf_(acc);          // silu
  float ssq = blk_sum(y * y, sred, tid);   // l2 over the head's 256 dims
  float r = rsqrtf(ssq + 1e-6f);
  float outv = y * r * (isK ? 1.f : 0.0625f);   // q gets Kd^-0.5
  (isK ? kf : qf)[(size_t)row * 1024 + c] = f2bf(outv);
}

// -------------------- causal conv(4) + SiLU for v (bf16 out) --------------------
__global__ __launch_bounds__(256) void conv_v_kernel(
    const u16* __restrict__ qkv, const float* __restrict__ cwv, u16* __restrict__ vf) {
  int row = blockIdx.x, tid = threadIdx.x;
  int t = row & 2047;
  int c0 = blockIdx.y * 1024 + tid * 4;    // channel in [0,2048)
  float a0 = 0, a1 = 0, a2 = 0, a3 = 0;
#pragma unroll
  for (int i = 0; i < 4; i++) {
    int tt = t - 3 + i;
    if (tt >= 0) {
      uint2 raw = *(const uint2*)(qkv + (size_t)(row - 3 + i) * 4096 + 2048 + c0);
      a0 = fmaf(cwv[(c0 + 0) * 4 + i], bf2f(raw.x & 0xffffu), a0);
      a1 = fmaf(cwv[(c0 + 1) * 4 + i], bf2f(raw.x >> 16), a1);
      a2 = fmaf(cwv[(c0 + 2) * 4 + i], bf2f(raw.y & 0xffffu), a2);
      a3 = fmaf(cwv[(c0 + 3) * 4 + i], bf2f(raw.y >> 16), a3);
    }
  }
  a0 = a0 * sigmoidf_(a0);
  a1 = a1 * sigmoidf_(a1);
  a2 = a2 * sigmoidf_(a2);
  a3 = a3 * sigmoidf_(a3);
  uint2 pk;
  pk.x = (uint32_t)f2bf(a0) | ((uint32_t)f2bf(a1) << 16);
  pk.y = (uint32_t)f2bf(a2) | ((uint32_t)f2bf(a3) << 16);
  *(uint2*)(vf + (size_t)row * 2048 + c0) = pk;
}

// -------------------- gated delta rule: column-parallel sequential scan --------------------
// 8192 independent (b,h,v) columns; 4 columns per wave; lane l owns k-dims 4l..4l+3.
// Vectorized loads (dwordx2 per k/q/v/gb) + software prefetch of step t+1 across
// the ~300-cycle compute chain of step t.
__global__ __launch_bounds__(256) void scan_kernel(
    const u16* __restrict__ q, const u16* __restrict__ k, const u16* __restrict__ v,
    const float2* __restrict__ gb, u16* __restrict__ o) {
  const int tid = threadIdx.x;
  const int lane = tid & 63;
  const int wv = tid >> 6;
  const int wg = blockIdx.x * 4 + wv;   // 0..2047
  const int c0 = wg * 4;
  const int b = c0 >> 11;
  const int hh = (c0 >> 9) & 3;
  const int v0 = c0 & 511;
  float S[4][4];                        // S[col][j], k index = 4*lane+j
#pragma unroll
  for (int cc = 0; cc < 4; cc++)
#pragma unroll
    for (int j = 0; j < 4; j++) S[cc][j] = 0.f;

  const u16* kp = k + (size_t)b * 2048 * 1024 + hh * 256 + 4 * lane;
  const u16* qp = q + (size_t)b * 2048 * 1024 + hh * 256 + 4 * lane;
  const u16* vp = v + (size_t)b * 2048 * 2048 + hh * 512 + v0;
  const float2* gp = gb + (size_t)b * 2048 * 4 + hh;
  u16* op = o + (size_t)b * 2048 * 2048 + hh * 512 + v0;

  uint2 kr = *(const uint2*)kp;
  uint2 qr = *(const uint2*)qp;
  uint2 vr = *(const uint2*)vp;
  float2 gv = *gp;

  for (int t = 0; t < 2048; t++) {
    uint2 krn, qrn, vrn; float2 gvn;
    if (t < 2047) {                      // uniform branch; prefetch next step
      kp += 1024; qp += 1024; vp += 2048; gp += 4;
      krn = *(const uint2*)kp;
      qrn = *(const uint2*)qp;
      vrn = *(const uint2*)vp;
      gvn = *gp;
    }
    const float eg = gv.x;               // exp(g_t), precomputed in k1
    const float bt = gv.y;
    float kk[4], qq[4];
    kk[0] = bflo(kr.x); kk[1] = bfhi(kr.x); kk[2] = bflo(kr.y); kk[3] = bfhi(kr.y);
    qq[0] = bflo(qr.x); qq[1] = bfhi(qr.x); qq[2] = bflo(qr.y); qq[3] = bfhi(qr.y);
    float vv0 = bflo(vr.x), vv1 = bfhi(vr.x), vv2 = bflo(vr.y), vv3 = bfhi(vr.y);
    float s01 = (lane & 1) ? vv1 : vv0;
    float s23 = (lane & 1) ? vv3 : vv2;
    float vsel = (lane & 2) ? s23 : s01; // v for column lane&3

    float p[4];
#pragma unroll
    for (int cc = 0; cc < 4; cc++) {
      S[cc][0] *= eg; S[cc][1] *= eg; S[cc][2] *= eg; S[cc][3] *= eg;
      p[cc] = fmaf(kk[0], S[cc][0], fmaf(kk[1], S[cc][1], fmaf(kk[2], S[cc][2], kk[3] * S[cc][3])));
    }
    // fold 4 column-partials into lane%4, then butterfly across the wave
    float t0 = __shfl_xor(p[0], 1), t1 = __shfl_xor(p[1], 1);
    float fa = (lane & 1) ? (p[1] + t1) : (p[0] + t0);
    float t2 = __shfl_xor(p[2], 1), t3 = __shfl_xor(p[3], 1);
    float fb = (lane & 1) ? (p[3] + t3) : (p[2] + t2);
    float ta = __shfl_xor(fa, 2), tb = __shfl_xor(fb, 2);
    float r = (lane & 2) ? (fb + tb) : (fa + ta);
    r += __shfl_xor(r, 4); r += __shfl_xor(r, 8); r += __shfl_xor(r, 16); r += __shfl_xor(r, 32);
    float dself = (vsel - r) * bt;       // delta for column lane&3
    float dv[4];
    dv[0] = __shfl(dself, 0); dv[1] = __shfl(dself, 1);
    dv[2] = __shfl(dself, 2); dv[3] = __shfl(dself, 3);
    float opd[4];
#pragma unroll
    for (int cc = 0; cc < 4; cc++) {
      S[cc][0] = fmaf(kk[0], dv[cc], S[cc][0]);
      S[cc][1] = fmaf(kk[1], dv[cc], S[cc][1]);
      S[cc][2] = fmaf(kk[2], dv[cc], S[cc][2]);
      S[cc][3] = fmaf(kk[3], dv[cc], S[cc][3]);
      opd[cc] = fmaf(qq[0], S[cc][0], fmaf(qq[1], S[cc][1], fmaf(qq[2], S[cc][2], qq[3] * S[cc][3])));
    }
    float u0 = __shfl_xor(opd[0], 1), u1 = __shfl_xor(opd[1], 1);
    float ga = (lane & 1) ? (opd[1] + u1) : (opd[0] + u0);
    float u2 = __shfl_xor(opd[2], 1), u3 = __shfl_xor(opd[3], 1);
    float gbv = (lane & 1) ? (opd[3] + u3) : (opd[2] + u2);
    float ua = __shfl_xor(ga, 2), ub = __shfl_xor(gbv, 2);
    float ro = (lane & 2) ? (gbv + ub) : (ga + ua);
    ro += __shfl_xor(ro, 4); ro += __shfl_xor(ro, 8); ro += __shfl_xor(ro, 16); ro += __shfl_xor(ro, 32);
    if (lane < 4) op[lane] = f2bf(ro);
    op += 2048;
    kr = krn; qr = qrn; vr = vrn; gv = gvn;
  }
}

// -------------------- gated RMS-norm of o: bf16 out --------------------
__global__ __launch_bounds__(256) void onorm_kernel(
    const u16* __restrict__ o, const u16* __restrict__ gate,
    const float* __restrict__ onw, u16* __restrict__ ofin) {
  __shared__ float sred[4];
  int row = blockIdx.x, hh = blockIdx.y, tid = threadIdx.x;
  size_t base = (size_t)row * 2048 + hh * 512;
  uint32_t oraw = *(const uint32_t*)(o + base + tid * 2);
  float o0 = bf2f(oraw & 0xffffu), o1 = bf2f(oraw >> 16);
  float ssq = blk_sum(o0 * o0 + o1 * o1, sred, tid);
  float rinv = rsqrtf(ssq * (1.f / 512.f) + 1e-6f);
  uint32_t graw = *(const uint32_t*)(gate + base + tid * 2);
  float g0 = bf2f(graw & 0xffffu), g1 = bf2f(graw >> 16);
  float r0 = o0 * rinv * onw[tid * 2 + 0] * (g0 * sigmoidf_(g0));
  float r1 = o1 * rinv * onw[tid * 2 + 1] * (g1 * sigmoidf_(g1));
  uint32_t pk = (uint32_t)f2bf(r0) | ((uint32_t)f2bf(r1) << 16);
  *(uint32_t*)(ofin + base + tid * 2) = pk;
}

// -------------------- LN2 --------------------
__global__ __launch_bounds__(256) void ln2_kernel(
    const float* __restrict__ x1, const float* __restrict__ g2, const float* __restrict__ b2,
    u16* __restrict__ h2) {
  __shared__ float sred[4];
  int row = blockIdx.x, tid = threadIdx.x;
  const float4 xv = ((const float4*)(x1 + (size_t)row * 1024))[tid];
  float ts  = blk_sum(xv.x + xv.y + xv.z + xv.w, sred, tid);
  float ts2 = blk_sum(xv.x * xv.x + xv.y * xv.y + xv.z * xv.z + xv.w * xv.w, sred, tid);
  float mean = ts * (1.f / 1024.f);
  float inv = rsqrtf(ts2 * (1.f / 1024.f) - mean * mean + 1e-5f);
  int c = tid * 4;
  float h0 = (xv.x - mean) * inv * g2[c + 0] + b2[c + 0];
  float h1 = (xv.y - mean) * inv * g2[c + 1] + b2[c + 1];
  float h2v = (xv.z - mean) * inv * g2[c + 2] + b2[c + 2];
  float h3 = (xv.w - mean) * inv * g2[c + 3] + b2[c + 3];
  uint2 pk;
  pk.x = (uint32_t)f2bf(h0) | ((uint32_t)f2bf(h1) << 16);
  pk.y = (uint32_t)f2bf(h2v) | ((uint32_t)f2bf(h3) << 16);
  *(uint2*)(h2 + (size_t)row * 1024 + c) = pk;
}

// ==================== launch ====================
// Workspace layout (bytes), total ~162.3 MB with liveness overlap:
//  [0,64M)    qkv_proj bf16 8192x4096   (gemm_qkv -> convs)
//  [0,32M)    obuf bf16 8192x2048       (scan -> onorm; overlays dead qkv lower half)
//  [32M,64M)  gate bf16 8192x2048       (gemm_gate -> onorm; overlays dead qkv upper half)
//  [64M,80M)  hbf bf16 8192x1024        (k1 -> gemm_gate)
//  [80M,88M)  WTqkv bf16 4096x1024
//  [88M,92M)  WgT bf16 2048x1024
//  [92M,96M)  WoT bf16 1024x2048
//  [96M,98M)  W2T bf16 1024x1024
//  [98M,114M) qf bf16 8192x1024         (conv -> scan)
//  [114M,130M)kf bf16 8192x1024         (conv -> scan)
//  [130M,162M)vf bf16 8192x2048         (conv -> scan)
//  [98M,130M) ofin bf16 8192x2048       (onorm -> gemm1; overlays dead qf/kf)
//  [130M,146M)h2bf bf16 8192x1024       (ln2 -> gemm2; overlays dead vf)
//  [162M,+)   gb2 float2 8192x4
// x1 (post-o_proj residual) lives in d_out itself.
extern "C" void kernel_launch(void* const* d_in, const int* in_sizes, int n_in,
                              void* d_out, int out_size, void* d_ws, size_t ws_size,
                              hipStream_t stream) {
  (void)in_sizes; (void)n_in; (void)out_size; (void)ws_size;
  const float* x    = (const float*)d_in[0];
  const float* ln1g = (const float*)d_in[1];
  const float* ln1b = (const float*)d_in[2];
  const float* ln2g = (const float*)d_in[3];
  const float* ln2b = (const float*)d_in[4];
  const float* rmsw = (const float*)d_in[5];
  const float* Wq   = (const float*)d_in[6];
  const float* Wk   = (const float*)d_in[7];
  const float* Wv   = (const float*)d_in[8];
  const float* cwq  = (const float*)d_in[9];
  const float* cwk  = (const float*)d_in[10];
  const float* cwv  = (const float*)d_in[11];
  const float* Wa   = (const float*)d_in[12];
  const float* dtb  = (const float*)d_in[13];
  const float* Alog = (const float*)d_in[14];
  const float* Wb   = (const float*)d_in[15];
  const float* Wg   = (const float*)d_in[16];
  const float* onw  = (const float*)d_in[17];
  const float* Wo   = (const float*)d_in[18];
  const float* W2   = (const float*)d_in[19];
  const float* b2   = (const float*)d_in[20];

  uint8_t* ws = (uint8_t*)d_ws;
  const size_t MB = 1024ull * 1024;
  u16*   qkvp  = (u16*)(ws);               // 64MB
  u16*   obuf  = (u16*)(ws);               // 32MB (overlay)
  u16*   gate  = (u16*)(ws + 32 * MB);     // 32MB (overlay)
  u16*   hbf   = (u16*)(ws + 64 * MB);     // 16MB
  u16*   WTqkv = (u16*)(ws + 80 * MB);     // 8MB
  u16*   WgT   = (u16*)(ws + 88 * MB);     // 4MB
  u16*   WoT   = (u16*)(ws + 92 * MB);     // 4MB
  u16*   W2T   = (u16*)(ws + 96 * MB);     // 2MB
  u16*   qf    = (u16*)(ws + 98 * MB);     // 16MB
  u16*   kf    = (u16*)(ws + 114 * MB);    // 16MB
  u16*   vf    = (u16*)(ws + 130 * MB);    // 32MB
  u16*   ofin  = (u16*)(ws + 98 * MB);     // 32MB (overlay qf/kf)
  u16*   h2bf  = (u16*)(ws + 130 * MB);    // 16MB (overlay vf)
  float2* gb2  = (float2*)(ws + 162 * MB); // 256KB
  float* x1    = (float*)d_out;            // residual stage lives in d_out
  float* outp  = (float*)d_out;

  dim3 tb(32, 8);
  transpose_w<<<dim3(32, 32), tb, 0, stream>>>(Wq, WTqkv,               1024, 1024);
  transpose_w<<<dim3(32, 32), tb, 0, stream>>>(Wk, WTqkv + 1024 * 1024, 1024, 1024);
  transpose_w<<<dim3(64, 32), tb, 0, stream>>>(Wv, WTqkv + 2048 * 1024, 1024, 2048);
  transpose_w<<<dim3(64, 32), tb, 0, stream>>>(Wg, WgT,                 1024, 2048);
  transpose_w<<<dim3(32, 64), tb, 0, stream>>>(Wo, WoT,                 2048, 1024);
  transpose_w<<<dim3(32, 32), tb, 0, stream>>>(W2, W2T,                 1024, 1024);

  k1_kernel<<<8192, 256, 0, stream>>>(x, ln1g, ln1b, rmsw, Wa, Wb, dtb, Alog, hbf, gb2);
  gemm_bt<0><<<dim3(32, 64), 256, 0, stream>>>(hbf, WTqkv, 8192, 4096, 1024, nullptr, qkvp, nullptr, nullptr);
  conv_qk_kernel<<<dim3(8192, 8), 256, 0, stream>>>(qkvp, cwq, cwk, qf, kf);
  conv_v_kernel<<<dim3(8192, 2), 256, 0, stream>>>(qkvp, cwv, vf);
  scan_kernel<<<512, 256, 0, stream>>>(qf, kf, vf, gb2, obuf);
  gemm_bt<0><<<dim3(16, 64), 256, 0, stream>>>(hbf, WgT, 8192, 2048, 1024, nullptr, gate, nullptr, nullptr);
  onorm_kernel<<<dim3(8192, 4), 256, 0, stream>>>(obuf, gate, onw, ofin);
  gemm_bt<1><<<dim3(8, 64), 256, 0, stream>>>(ofin, WoT, 8192, 1024, 2048, x1, nullptr, x, nullptr);
  ln2_kernel<<<8192, 256, 0, stream>>>(x1, ln2g, ln2b, h2bf);
  gemm_bt<2><<<dim3(8, 64), 256, 0, stream>>>(h2bf, W2T, 8192, 1024, 1024, outp, nullptr, x1, b2);
}

// Round 4
// 1913.464 us; speedup vs baseline: 1.3095x; 1.1948x over previous
//
#include <hip/hip_runtime.h>
#include <stdint.h>

typedef uint16_t u16;
typedef __attribute__((ext_vector_type(8))) __bf16 bfrag8;
typedef __attribute__((ext_vector_type(4))) float f32x4;

#define DEV __device__ __forceinline__

DEV float bf2f(uint32_t lo16) { return __uint_as_float(lo16 << 16); }
DEV float bflo(uint32_t u) { return __uint_as_float(u << 16); }
DEV float bfhi(uint32_t u) { return __uint_as_float(u & 0xffff0000u); }
DEV u16 f2bf(float f) {
  uint32_t u = __float_as_uint(f);
  u += 0x7fffu + ((u >> 16) & 1u);   // RNE
  return (u16)(u >> 16);
}
DEV float sigmoidf_(float x) { return 1.f / (1.f + __expf(-x)); }

// ---- DPP 16-lane reduction (no LDS/DS ops; pure VALU) ----
// quad_perm[1,0,3,2]=0xB1 (xor1), quad_perm[2,3,0,1]=0x4E (xor2),
// row_half_mirror=0x141 (xor7 within 8), row_mirror=0x140 (xor15 within 16)
DEV float dpp_add(float x, const int ctrl) {
  int y;
  switch (ctrl) {   // ctrl must be a literal for the builtin; switch keeps call sites tidy
    case 0xB1:  y = __builtin_amdgcn_update_dpp(0, __float_as_int(x), 0xB1, 0xF, 0xF, true); break;
    case 0x4E:  y = __builtin_amdgcn_update_dpp(0, __float_as_int(x), 0x4E, 0xF, 0xF, true); break;
    case 0x141: y = __builtin_amdgcn_update_dpp(0, __float_as_int(x), 0x141, 0xF, 0xF, true); break;
    default:    y = __builtin_amdgcn_update_dpp(0, __float_as_int(x), 0x140, 0xF, 0xF, true); break;
  }
  return x + __int_as_float(y);
}
DEV float red16(float x) {
  x = dpp_add(x, 0xB1);
  x = dpp_add(x, 0x4E);
  x = dpp_add(x, 0x141);
  x = dpp_add(x, 0x140);
  return x;
}

DEV void unpack8(float* dst, uint4 r) {
  dst[0] = bflo(r.x); dst[1] = bfhi(r.x);
  dst[2] = bflo(r.y); dst[3] = bfhi(r.y);
  dst[4] = bflo(r.z); dst[5] = bfhi(r.z);
  dst[6] = bflo(r.w); dst[7] = bfhi(r.w);
}

// block-wide (256-thread) sum; caller must call uniformly
DEV float blk_sum(float v, float* sred, int tid) {
#pragma unroll
  for (int m = 32; m >= 1; m >>= 1) v += __shfl_xor(v, m);
  __syncthreads();                       // protect previous read of sred
  if ((tid & 63) == 0) sred[tid >> 6] = v;
  __syncthreads();
  return sred[0] + sred[1] + sred[2] + sred[3];
}

// -------------------- weight transpose fp32[K,N] -> bf16[N,K] --------------------
__global__ __launch_bounds__(256) void transpose_w(const float* __restrict__ W,
                                                   u16* __restrict__ WT, int Kd_, int Nd_) {
  __shared__ float tile[32][33];
  int tx = threadIdx.x, ty = threadIdx.y;
  int n0 = blockIdx.x * 32, k0 = blockIdx.y * 32;
#pragma unroll
  for (int i = ty; i < 32; i += 8) tile[i][tx] = W[(size_t)(k0 + i) * Nd_ + n0 + tx];
  __syncthreads();
#pragma unroll
  for (int i = ty; i < 32; i += 8) WT[(size_t)(n0 + i) * Kd_ + k0 + tx] = f2bf(tile[tx][i]);
}

// -------------------- LN1 + RMSnorm + (h@Wa, h@Wb -> {exp(g), beta}) --------------------
__global__ __launch_bounds__(256) void k1_kernel(
    const float* __restrict__ x, const float* __restrict__ ln1g, const float* __restrict__ ln1b,
    const float* __restrict__ rmsw, const float* __restrict__ Wa, const float* __restrict__ Wb,
    const float* __restrict__ dtb, const float* __restrict__ Alog,
    u16* __restrict__ hbf, float2* __restrict__ gb2) {
  __shared__ float sred[4];
  int row = blockIdx.x, tid = threadIdx.x;
  const float4 xv = ((const float4*)(x + (size_t)row * 1024))[tid];
  float ts  = blk_sum(xv.x + xv.y + xv.z + xv.w, sred, tid);
  float ts2 = blk_sum(xv.x * xv.x + xv.y * xv.y + xv.z * xv.z + xv.w * xv.w, sred, tid);
  float mean = ts * (1.f / 1024.f);
  float var  = ts2 * (1.f / 1024.f) - mean * mean;
  float inv  = rsqrtf(var + 1e-5f);
  int c = tid * 4;
  float l0 = (xv.x - mean) * inv * ln1g[c + 0] + ln1b[c + 0];
  float l1 = (xv.y - mean) * inv * ln1g[c + 1] + ln1b[c + 1];
  float l2 = (xv.z - mean) * inv * ln1g[c + 2] + ln1b[c + 2];
  float l3 = (xv.w - mean) * inv * ln1g[c + 3] + ln1b[c + 3];
  float ssq = blk_sum(l0 * l0 + l1 * l1 + l2 * l2 + l3 * l3, sred, tid);
  float rinv = rsqrtf(ssq * (1.f / 1024.f) + 1e-6f);
  float h0 = l0 * rinv * rmsw[c + 0];
  float h1 = l1 * rinv * rmsw[c + 1];
  float h2 = l2 * rinv * rmsw[c + 2];
  float h3 = l3 * rinv * rmsw[c + 3];
  uint2 pk;
  pk.x = (uint32_t)f2bf(h0) | ((uint32_t)f2bf(h1) << 16);
  pk.y = (uint32_t)f2bf(h2) | ((uint32_t)f2bf(h3) << 16);
  *(uint2*)(hbf + (size_t)row * 1024 + c) = pk;
  float hv[4] = {h0, h1, h2, h3};
  float pa[4] = {0, 0, 0, 0}, pb[4] = {0, 0, 0, 0};
#pragma unroll
  for (int e = 0; e < 4; e++) {
    const float* wa = Wa + (size_t)(c + e) * 4;
    const float* wb = Wb + (size_t)(c + e) * 4;
#pragma unroll
    for (int p = 0; p < 4; p++) {
      pa[p] = fmaf(hv[e], wa[p], pa[p]);
      pb[p] = fmaf(hv[e], wb[p], pb[p]);
    }
  }
  float ra[4], rb[4];
  for (int p = 0; p < 4; p++) ra[p] = blk_sum(pa[p], sred, tid);
  for (int p = 0; p < 4; p++) rb[p] = blk_sum(pb[p], sred, tid);
  if (tid < 4) {
    float z = ra[tid] + dtb[tid];
    float sp = fmaxf(z, 0.f) + log1pf(expf(-fabsf(z)));   // stable softplus
    float gg = -expf(Alog[tid]) * sp;
    float2 o2;
    o2.x = expf(gg);                       // scan only ever needs exp(g)
    o2.y = 1.f / (1.f + expf(-rb[tid]));
    gb2[(size_t)row * 4 + tid] = o2;
  }
}

// -------------------- bf16 MFMA GEMM: C[M,N] = A[M,K] * Bt[N,K]^T --------------------
// MODE 0: outh = bf16(acc); MODE 1: outf = acc + res; MODE 2: outf = gelu(acc+bias) + res
template <int MODE>
__global__ __launch_bounds__(256) void gemm_bt(
    const u16* __restrict__ A, const u16* __restrict__ Bt, int M, int N, int K,
    float* __restrict__ outf, u16* __restrict__ outh,
    const float* __restrict__ res, const float* __restrict__ bias) {
  __shared__ u16 As[128 * 64];
  __shared__ u16 Bs[128 * 64];
  const int tid = threadIdx.x;
  const int lane = tid & 63;
  const int wv = tid >> 6;
  const int quad = lane >> 4;
  const int l16 = lane & 15;
  const int waveM = (wv & 1) * 64;
  const int waveN = (wv >> 1) * 64;
  const size_t arow0 = (size_t)blockIdx.y * 128;
  const size_t brow0 = (size_t)blockIdx.x * 128;
  const int srow = tid >> 3;          // 0..31
  const int soff = (tid & 7) * 8;     // 16B chunks within a 64-elem row
  f32x4 acc[4][4];
#pragma unroll
  for (int i = 0; i < 4; i++)
#pragma unroll
    for (int j = 0; j < 4; j++) acc[i][j] = (f32x4){0.f, 0.f, 0.f, 0.f};

  for (int k0 = 0; k0 < K; k0 += 64) {
    __syncthreads();
#pragma unroll
    for (int i = 0; i < 4; i++) {
      int r = i * 32 + srow;
      *(int4*)(As + r * 64 + soff) = *(const int4*)(A + (arow0 + r) * K + k0 + soff);
      *(int4*)(Bs + r * 64 + soff) = *(const int4*)(Bt + (brow0 + r) * K + k0 + soff);
    }
    __syncthreads();
#pragma unroll
    for (int kk = 0; kk < 2; kk++) {
      bfrag8 af[4], bfr[4];
#pragma unroll
      for (int i = 0; i < 4; i++) {
        af[i]  = *(const bfrag8*)(As + (waveM + i * 16 + l16) * 64 + kk * 32 + quad * 8);
        bfr[i] = *(const bfrag8*)(Bs + (waveN + i * 16 + l16) * 64 + kk * 32 + quad * 8);
      }
#pragma unroll
      for (int i = 0; i < 4; i++)
#pragma unroll
        for (int j = 0; j < 4; j++)
          acc[i][j] = __builtin_amdgcn_mfma_f32_16x16x32_bf16(af[i], bfr[j], acc[i][j], 0, 0, 0);
    }
  }
#pragma unroll
  for (int i = 0; i < 4; i++) {
    int r0 = (int)arow0 + waveM + i * 16 + quad * 4;
#pragma unroll
    for (int j = 0; j < 4; j++) {
      int cN = (int)brow0 + waveN + j * 16 + l16;
#pragma unroll
      for (int r = 0; r < 4; r++) {
        size_t idx = (size_t)(r0 + r) * N + cN;
        float vacc = acc[i][j][r];
        if (MODE == 0) {
          outh[idx] = f2bf(vacc);
        } else if (MODE == 1) {
          outf[idx] = vacc + res[idx];
        } else {
          float z = vacc + bias[cN];
          float ge = 0.5f * z * (1.f + erff(z * 0.70710678118654752f));
          outf[idx] = ge + res[idx];
        }
      }
    }
  }
}

// -------------------- causal conv(4) + SiLU + L2norm for q,k (bf16 out) --------------------
// qkv layout: [row, 4096] = [q(1024) | k(1024) | v(2048)]
__global__ __launch_bounds__(256) void conv_qk_kernel(
    const u16* __restrict__ qkv, const float* __restrict__ cwq, const float* __restrict__ cwk,
    u16* __restrict__ qf, u16* __restrict__ kf) {
  __shared__ float sred[4];
  int row = blockIdx.x, tid = threadIdx.x;
  int t = row & 2047;
  int isK = (blockIdx.y >= 4);
  int hh = blockIdx.y & 3;
  int c = hh * 256 + tid;                  // channel within the 1024-wide projection
  const float* cw = isK ? cwk : cwq;
  int col = (isK ? 1024 : 0) + c;          // column in qkv
  float acc = 0.f;
#pragma unroll
  for (int i = 0; i < 4; i++) {
    int tt = t - 3 + i;
    if (tt >= 0) acc = fmaf(cw[c * 4 + i], bf2f(qkv[(size_t)(row - 3 + i) * 4096 + col]), acc);
  }
  float y = acc * sigmoidf_(acc);          // silu
  float ssq = blk_sum(y * y, sred, tid);   // l2 over the head's 256 dims
  float r = rsqrtf(ssq + 1e-6f);
  float outv = y * r * (isK ? 1.f : 0.0625f);   // q gets Kd^-0.5
  (isK ? kf : qf)[(size_t)row * 1024 + c] = f2bf(outv);
}

// -------------------- causal conv(4) + SiLU for v (bf16 out) --------------------
__global__ __launch_bounds__(256) void conv_v_kernel(
    const u16* __restrict__ qkv, const float* __restrict__ cwv, u16* __restrict__ vf) {
  int row = blockIdx.x, tid = threadIdx.x;
  int t = row & 2047;
  int c0 = blockIdx.y * 1024 + tid * 4;    // channel in [0,2048)
  float a0 = 0, a1 = 0, a2 = 0, a3 = 0;
#pragma unroll
  for (int i = 0; i < 4; i++) {
    int tt = t - 3 + i;
    if (tt >= 0) {
      uint2 raw = *(const uint2*)(qkv + (size_t)(row - 3 + i) * 4096 + 2048 + c0);
      a0 = fmaf(cwv[(c0 + 0) * 4 + i], bf2f(raw.x & 0xffffu), a0);
      a1 = fmaf(cwv[(c0 + 1) * 4 + i], bf2f(raw.x >> 16), a1);
      a2 = fmaf(cwv[(c0 + 2) * 4 + i], bf2f(raw.y & 0xffffu), a2);
      a3 = fmaf(cwv[(c0 + 3) * 4 + i], bf2f(raw.y >> 16), a3);
    }
  }
  a0 = a0 * sigmoidf_(a0);
  a1 = a1 * sigmoidf_(a1);
  a2 = a2 * sigmoidf_(a2);
  a3 = a3 * sigmoidf_(a3);
  uint2 pk;
  pk.x = (uint32_t)f2bf(a0) | ((uint32_t)f2bf(a1) << 16);
  pk.y = (uint32_t)f2bf(a2) | ((uint32_t)f2bf(a3) << 16);
  *(uint2*)(vf + (size_t)row * 2048 + c0) = pk;
}

// -------------------- gated delta rule: DPP-group sequential scan --------------------
// 8192 independent (b,h,v) columns. Each 16-lane group owns ONE column with all 256
// k-dims (16 fp32 state regs per lane: k-dims 16*l16..+16). A wave = 4 groups = 4
// columns of the same (b,h). All reductions are 16-lane DPP butterflies (pure VALU,
// zero DS ops); no cross-group communication exists.
__global__ __launch_bounds__(256) void scan_kernel(
    const u16* __restrict__ q, const u16* __restrict__ k, const u16* __restrict__ v,
    const float2* __restrict__ gb, u16* __restrict__ o) {
  const int tid = threadIdx.x;
  const int lane = tid & 63;
  const int wv = tid >> 6;
  const int wg = blockIdx.x * 4 + wv;   // 0..2047
  const int c0 = wg * 4;
  const int b = c0 >> 11;
  const int hh = (c0 >> 9) & 3;
  const int v0 = c0 & 511;
  const int gidx = lane >> 4;           // group -> column v0+gidx
  const int l16 = lane & 15;            // k-dims [16*l16, 16*l16+16)

  float S[16];
#pragma unroll
  for (int j = 0; j < 16; j++) S[j] = 0.f;

  const u16* kp = k + (size_t)b * 2048 * 1024 + hh * 256 + l16 * 16;
  const u16* qp = q + (size_t)b * 2048 * 1024 + hh * 256 + l16 * 16;
  const u16* vp = v + (size_t)b * 2048 * 2048 + hh * 512 + v0 + gidx;
  const float2* gp = gb + (size_t)b * 2048 * 4 + hh;
  u16* op = o + (size_t)b * 2048 * 2048 + hh * 512 + v0 + gidx;

  uint4 kr0 = *(const uint4*)kp, kr1 = *(const uint4*)(kp + 8);
  uint4 qr0 = *(const uint4*)qp, qr1 = *(const uint4*)(qp + 8);
  u16 vr = *vp;
  float2 gv = *gp;

  for (int t = 0; t < 2048; t++) {
    uint4 kn0, kn1, qn0, qn1; u16 vn; float2 gn;
    if (t < 2047) {                     // uniform branch; prefetch next step
      kp += 1024; qp += 1024; vp += 2048; gp += 4;
      kn0 = *(const uint4*)kp; kn1 = *(const uint4*)(kp + 8);
      qn0 = *(const uint4*)qp; qn1 = *(const uint4*)(qp + 8);
      vn = *vp; gn = *gp;
    }
    float kk[16], qq[16];
    unpack8(kk, kr0); unpack8(kk + 8, kr1);
    unpack8(qq, qr0); unpack8(qq + 8, qr1);
    float vt = bf2f(vr);
    const float eg = gv.x, bt = gv.y;

#pragma unroll
    for (int j = 0; j < 16; j++) S[j] *= eg;          // decay
    float d0 = 0, d1 = 0, d2 = 0, d3 = 0;
#pragma unroll
    for (int j = 0; j < 4; j++) {                     // kv = k . S (per-lane partial)
      d0 = fmaf(kk[j],      S[j],      d0);
      d1 = fmaf(kk[4 + j],  S[4 + j],  d1);
      d2 = fmaf(kk[8 + j],  S[8 + j],  d2);
      d3 = fmaf(kk[12 + j], S[12 + j], d3);
    }
    float r = red16((d0 + d1) + (d2 + d3));           // 16-lane DPP reduce
    float dl = (vt - r) * bt;                         // delta (every lane has it)
    float e0 = 0, e1 = 0, e2 = 0, e3 = 0;
#pragma unroll
    for (int j = 0; j < 4; j++) {                     // S += k (x) delta;  o = q . S
      S[j]      = fmaf(kk[j],      dl, S[j]);       e0 = fmaf(qq[j],      S[j],      e0);
      S[4 + j]  = fmaf(kk[4 + j],  dl, S[4 + j]);   e1 = fmaf(qq[4 + j],  S[4 + j],  e1);
      S[8 + j]  = fmaf(kk[8 + j],  dl, S[8 + j]);   e2 = fmaf(qq[8 + j],  S[8 + j],  e2);
      S[12 + j] = fmaf(kk[12 + j], dl, S[12 + j]);  e3 = fmaf(qq[12 + j], S[12 + j], e3);
    }
    float ro = red16((e0 + e1) + (e2 + e3));
    if (l16 == 0) *op = f2bf(ro);
    op += 2048;
    kr0 = kn0; kr1 = kn1; qr0 = qn0; qr1 = qn1; vr = vn; gv = gn;
  }
}

// -------------------- gated RMS-norm of o: bf16 out --------------------
__global__ __launch_bounds__(256) void onorm_kernel(
    const u16* __restrict__ o, const u16* __restrict__ gate,
    const float* __restrict__ onw, u16* __restrict__ ofin) {
  __shared__ float sred[4];
  int row = blockIdx.x, hh = blockIdx.y, tid = threadIdx.x;
  size_t base = (size_t)row * 2048 + hh * 512;
  uint32_t oraw = *(const uint32_t*)(o + base + tid * 2);
  float o0 = bf2f(oraw & 0xffffu), o1 = bf2f(oraw >> 16);
  float ssq = blk_sum(o0 * o0 + o1 * o1, sred, tid);
  float rinv = rsqrtf(ssq * (1.f / 512.f) + 1e-6f);
  uint32_t graw = *(const uint32_t*)(gate + base + tid * 2);
  float g0 = bf2f(graw & 0xffffu), g1 = bf2f(graw >> 16);
  float r0 = o0 * rinv * onw[tid * 2 + 0] * (g0 * sigmoidf_(g0));
  float r1 = o1 * rinv * onw[tid * 2 + 1] * (g1 * sigmoidf_(g1));
  uint32_t pk = (uint32_t)f2bf(r0) | ((uint32_t)f2bf(r1) << 16);
  *(uint32_t*)(ofin + base + tid * 2) = pk;
}

// -------------------- LN2 --------------------
__global__ __launch_bounds__(256) void ln2_kernel(
    const float* __restrict__ x1, const float* __restrict__ g2, const float* __restrict__ b2,
    u16* __restrict__ h2) {
  __shared__ float sred[4];
  int row = blockIdx.x, tid = threadIdx.x;
  const float4 xv = ((const float4*)(x1 + (size_t)row * 1024))[tid];
  float ts  = blk_sum(xv.x + xv.y + xv.z + xv.w, sred, tid);
  float ts2 = blk_sum(xv.x * xv.x + xv.y * xv.y + xv.z * xv.z + xv.w * xv.w, sred, tid);
  float mean = ts * (1.f / 1024.f);
  float inv = rsqrtf(ts2 * (1.f / 1024.f) - mean * mean + 1e-5f);
  int c = tid * 4;
  float h0 = (xv.x - mean) * inv * g2[c + 0] + b2[c + 0];
  float h1 = (xv.y - mean) * inv * g2[c + 1] + b2[c + 1];
  float h2v = (xv.z - mean) * inv * g2[c + 2] + b2[c + 2];
  float h3 = (xv.w - mean) * inv * g2[c + 3] + b2[c + 3];
  uint2 pk;
  pk.x = (uint32_t)f2bf(h0) | ((uint32_t)f2bf(h1) << 16);
  pk.y = (uint32_t)f2bf(h2v) | ((uint32_t)f2bf(h3) << 16);
  *(uint2*)(h2 + (size_t)row * 1024 + c) = pk;
}

// ==================== launch ====================
// Workspace layout (bytes), total ~162.3 MB with liveness overlap:
//  [0,64M)    qkv_proj bf16 8192x4096   (gemm_qkv -> convs)
//  [0,32M)    obuf bf16 8192x2048       (scan -> onorm; overlays dead qkv lower half)
//  [32M,64M)  gate bf16 8192x2048       (gemm_gate -> onorm; overlays dead qkv upper half)
//  [64M,80M)  hbf bf16 8192x1024        (k1 -> gemm_gate)
//  [80M,88M)  WTqkv bf16 4096x1024
//  [88M,92M)  WgT bf16 2048x1024
//  [92M,96M)  WoT bf16 1024x2048
//  [96M,98M)  W2T bf16 1024x1024
//  [98M,114M) qf bf16 8192x1024         (conv -> scan)
//  [114M,130M)kf bf16 8192x1024         (conv -> scan)
//  [130M,162M)vf bf16 8192x2048         (conv -> scan)
//  [98M,130M) ofin bf16 8192x2048       (onorm -> gemm1; overlays dead qf/kf)
//  [130M,146M)h2bf bf16 8192x1024       (ln2 -> gemm2; overlays dead vf)
//  [162M,+)   gb2 float2 8192x4
// x1 (post-o_proj residual) lives in d_out itself.
extern "C" void kernel_launch(void* const* d_in, const int* in_sizes, int n_in,
                              void* d_out, int out_size, void* d_ws, size_t ws_size,
                              hipStream_t stream) {
  (void)in_sizes; (void)n_in; (void)out_size; (void)ws_size;
  const float* x    = (const float*)d_in[0];
  const float* ln1g = (const float*)d_in[1];
  const float* ln1b = (const float*)d_in[2];
  const float* ln2g = (const float*)d_in[3];
  const float* ln2b = (const float*)d_in[4];
  const float* rmsw = (const float*)d_in[5];
  const float* Wq   = (const float*)d_in[6];
  const float* Wk   = (const float*)d_in[7];
  const float* Wv   = (const float*)d_in[8];
  const float* cwq  = (const float*)d_in[9];
  const float* cwk  = (const float*)d_in[10];
  const float* cwv  = (const float*)d_in[11];
  const float* Wa   = (const float*)d_in[12];
  const float* dtb  = (const float*)d_in[13];
  const float* Alog = (const float*)d_in[14];
  const float* Wb   = (const float*)d_in[15];
  const float* Wg   = (const float*)d_in[16];
  const float* onw  = (const float*)d_in[17];
  const float* Wo   = (const float*)d_in[18];
  const float* W2   = (const float*)d_in[19];
  const float* b2   = (const float*)d_in[20];

  uint8_t* ws = (uint8_t*)d_ws;
  const size_t MB = 1024ull * 1024;
  u16*   qkvp  = (u16*)(ws);               // 64MB
  u16*   obuf  = (u16*)(ws);               // 32MB (overlay)
  u16*   gate  = (u16*)(ws + 32 * MB);     // 32MB (overlay)
  u16*   hbf   = (u16*)(ws + 64 * MB);     // 16MB
  u16*   WTqkv = (u16*)(ws + 80 * MB);     // 8MB
  u16*   WgT   = (u16*)(ws + 88 * MB);     // 4MB
  u16*   WoT   = (u16*)(ws + 92 * MB);     // 4MB
  u16*   W2T   = (u16*)(ws + 96 * MB);     // 2MB
  u16*   qf    = (u16*)(ws + 98 * MB);     // 16MB
  u16*   kf    = (u16*)(ws + 114 * MB);    // 16MB
  u16*   vf    = (u16*)(ws + 130 * MB);    // 32MB
  u16*   ofin  = (u16*)(ws + 98 * MB);     // 32MB (overlay qf/kf)
  u16*   h2bf  = (u16*)(ws + 130 * MB);    // 16MB (overlay vf)
  float2* gb2  = (float2*)(ws + 162 * MB); // 256KB
  float* x1    = (float*)d_out;            // residual stage lives in d_out
  float* outp  = (float*)d_out;

  dim3 tb(32, 8);
  transpose_w<<<dim3(32, 32), tb, 0, stream>>>(Wq, WTqkv,               1024, 1024);
  transpose_w<<<dim3(32, 32), tb, 0, stream>>>(Wk, WTqkv + 1024 * 1024, 1024, 1024);
  transpose_w<<<dim3(64, 32), tb, 0, stream>>>(Wv, WTqkv + 2048 * 1024, 1024, 2048);
  transpose_w<<<dim3(64, 32), tb, 0, stream>>>(Wg, WgT,                 1024, 2048);
  transpose_w<<<dim3(32, 64), tb, 0, stream>>>(Wo, WoT,                 2048, 1024);
  transpose_w<<<dim3(32, 32), tb, 0, stream>>>(W2, W2T,                 1024, 1024);

  k1_kernel<<<8192, 256, 0, stream>>>(x, ln1g, ln1b, rmsw, Wa, Wb, dtb, Alog, hbf, gb2);
  gemm_bt<0><<<dim3(32, 64), 256, 0, stream>>>(hbf, WTqkv, 8192, 4096, 1024, nullptr, qkvp, nullptr, nullptr);
  conv_qk_kernel<<<dim3(8192, 8), 256, 0, stream>>>(qkvp, cwq, cwk, qf, kf);
  conv_v_kernel<<<dim3(8192, 2), 256, 0, stream>>>(qkvp, cwv, vf);
  scan_kernel<<<512, 256, 0, stream>>>(qf, kf, vf, gb2, obuf);
  gemm_bt<0><<<dim3(16, 64), 256, 0, stream>>>(hbf, WgT, 8192, 2048, 1024, nullptr, gate, nullptr, nullptr);
  onorm_kernel<<<dim3(8192, 4), 256, 0, stream>>>(obuf, gate, onw, ofin);
  gemm_bt<1><<<dim3(8, 64), 256, 0, stream>>>(ofin, WoT, 8192, 1024, 2048, x1, nullptr, x, nullptr);
  ln2_kernel<<<8192, 256, 0, stream>>>(x1, ln2g, ln2b, h2bf);
  gemm_bt<2><<<dim3(8, 64), 256, 0, stream>>>(h2bf, W2T, 8192, 1024, 1024, outp, nullptr, x1, b2);
}

// Round 5
// 922.850 us; speedup vs baseline: 2.7151x; 2.0734x over previous
//
#include <hip/hip_runtime.h>
#include <stdint.h>

typedef uint16_t u16;
typedef __attribute__((ext_vector_type(8))) __bf16 bfrag8;
typedef __attribute__((ext_vector_type(4))) float f32x4;

#define DEV __device__ __forceinline__

DEV float bf2f(uint32_t lo16) { return __uint_as_float(lo16 << 16); }
DEV u16 f2bf(float f) {
  uint32_t u = __float_as_uint(f);
  u += 0x7fffu + ((u >> 16) & 1u);   // RNE
  return (u16)(u >> 16);
}
DEV uint32_t pack2(float a, float b) { return (uint32_t)f2bf(a) | ((uint32_t)f2bf(b) << 16); }
DEV float sigmoidf_(float x) { return 1.f / (1.f + __expf(-x)); }

// block-wide (256-thread) sum; caller must call uniformly
DEV float blk_sum(float v, float* sred, int tid) {
#pragma unroll
  for (int m = 32; m >= 1; m >>= 1) v += __shfl_xor(v, m);
  __syncthreads();
  if ((tid & 63) == 0) sred[tid >> 6] = v;
  __syncthreads();
  return sred[0] + sred[1] + sred[2] + sred[3];
}

// -------------------- weight transpose fp32[K,N] -> bf16[N,K] --------------------
__global__ __launch_bounds__(256) void transpose_w(const float* __restrict__ W,
                                                   u16* __restrict__ WT, int Kd_, int Nd_) {
  __shared__ float tile[32][33];
  int tx = threadIdx.x, ty = threadIdx.y;
  int n0 = blockIdx.x * 32, k0 = blockIdx.y * 32;
#pragma unroll
  for (int i = ty; i < 32; i += 8) tile[i][tx] = W[(size_t)(k0 + i) * Nd_ + n0 + tx];
  __syncthreads();
#pragma unroll
  for (int i = ty; i < 32; i += 8) WT[(size_t)(n0 + i) * Kd_ + k0 + tx] = f2bf(tile[tx][i]);
}

// -------------------- LN1 + RMSnorm + (h@Wa, h@Wb -> {g, beta}) --------------------
__global__ __launch_bounds__(256) void k1_kernel(
    const float* __restrict__ x, const float* __restrict__ ln1g, const float* __restrict__ ln1b,
    const float* __restrict__ rmsw, const float* __restrict__ Wa, const float* __restrict__ Wb,
    const float* __restrict__ dtb, const float* __restrict__ Alog,
    u16* __restrict__ hbf, float2* __restrict__ gb2) {
  __shared__ float sred[4];
  int row = blockIdx.x, tid = threadIdx.x;
  const float4 xv = ((const float4*)(x + (size_t)row * 1024))[tid];
  float ts  = blk_sum(xv.x + xv.y + xv.z + xv.w, sred, tid);
  float ts2 = blk_sum(xv.x * xv.x + xv.y * xv.y + xv.z * xv.z + xv.w * xv.w, sred, tid);
  float mean = ts * (1.f / 1024.f);
  float var  = ts2 * (1.f / 1024.f) - mean * mean;
  float inv  = rsqrtf(var + 1e-5f);
  int c = tid * 4;
  float l0 = (xv.x - mean) * inv * ln1g[c + 0] + ln1b[c + 0];
  float l1 = (xv.y - mean) * inv * ln1g[c + 1] + ln1b[c + 1];
  float l2 = (xv.z - mean) * inv * ln1g[c + 2] + ln1b[c + 2];
  float l3 = (xv.w - mean) * inv * ln1g[c + 3] + ln1b[c + 3];
  float ssq = blk_sum(l0 * l0 + l1 * l1 + l2 * l2 + l3 * l3, sred, tid);
  float rinv = rsqrtf(ssq * (1.f / 1024.f) + 1e-6f);
  float h0 = l0 * rinv * rmsw[c + 0];
  float h1 = l1 * rinv * rmsw[c + 1];
  float h2 = l2 * rinv * rmsw[c + 2];
  float h3 = l3 * rinv * rmsw[c + 3];
  uint2 pk;
  pk.x = pack2(h0, h1);
  pk.y = pack2(h2, h3);
  *(uint2*)(hbf + (size_t)row * 1024 + c) = pk;
  float hv[4] = {h0, h1, h2, h3};
  float pa[4] = {0, 0, 0, 0}, pb[4] = {0, 0, 0, 0};
#pragma unroll
  for (int e = 0; e < 4; e++) {
    const float* wa = Wa + (size_t)(c + e) * 4;
    const float* wb = Wb + (size_t)(c + e) * 4;
#pragma unroll
    for (int p = 0; p < 4; p++) {
      pa[p] = fmaf(hv[e], wa[p], pa[p]);
      pb[p] = fmaf(hv[e], wb[p], pb[p]);
    }
  }
  float ra[4], rb[4];
  for (int p = 0; p < 4; p++) ra[p] = blk_sum(pa[p], sred, tid);
  for (int p = 0; p < 4; p++) rb[p] = blk_sum(pb[p], sred, tid);
  if (tid < 4) {
    float z = ra[tid] + dtb[tid];
    float sp = fmaxf(z, 0.f) + log1pf(expf(-fabsf(z)));   // stable softplus
    float2 o2;
    o2.x = -expf(Alog[tid]) * sp;          // log-decay g
    o2.y = 1.f / (1.f + expf(-rb[tid]));   // beta
    gb2[(size_t)row * 4 + tid] = o2;
  }
}

// -------------------- bf16 MFMA GEMM: C[M,N] = A[M,K] * Bt[N,K]^T --------------------
template <int MODE>
__global__ __launch_bounds__(256) void gemm_bt(
    const u16* __restrict__ A, const u16* __restrict__ Bt, int M, int N, int K,
    float* __restrict__ outf, u16* __restrict__ outh,
    const float* __restrict__ res, const float* __restrict__ bias) {
  __shared__ u16 As[128 * 64];
  __shared__ u16 Bs[128 * 64];
  const int tid = threadIdx.x;
  const int lane = tid & 63;
  const int wv = tid >> 6;
  const int quad = lane >> 4;
  const int l16 = lane & 15;
  const int waveM = (wv & 1) * 64;
  const int waveN = (wv >> 1) * 64;
  const size_t arow0 = (size_t)blockIdx.y * 128;
  const size_t brow0 = (size_t)blockIdx.x * 128;
  const int srow = tid >> 3;
  const int soff = (tid & 7) * 8;
  f32x4 acc[4][4];
#pragma unroll
  for (int i = 0; i < 4; i++)
#pragma unroll
    for (int j = 0; j < 4; j++) acc[i][j] = (f32x4){0.f, 0.f, 0.f, 0.f};

  for (int k0 = 0; k0 < K; k0 += 64) {
    __syncthreads();
#pragma unroll
    for (int i = 0; i < 4; i++) {
      int r = i * 32 + srow;
      *(int4*)(As + r * 64 + soff) = *(const int4*)(A + (arow0 + r) * K + k0 + soff);
      *(int4*)(Bs + r * 64 + soff) = *(const int4*)(Bt + (brow0 + r) * K + k0 + soff);
    }
    __syncthreads();
#pragma unroll
    for (int kk = 0; kk < 2; kk++) {
      bfrag8 af[4], bfr[4];
#pragma unroll
      for (int i = 0; i < 4; i++) {
        af[i]  = *(const bfrag8*)(As + (waveM + i * 16 + l16) * 64 + kk * 32 + quad * 8);
        bfr[i] = *(const bfrag8*)(Bs + (waveN + i * 16 + l16) * 64 + kk * 32 + quad * 8);
      }
#pragma unroll
      for (int i = 0; i < 4; i++)
#pragma unroll
        for (int j = 0; j < 4; j++)
          acc[i][j] = __builtin_amdgcn_mfma_f32_16x16x32_bf16(af[i], bfr[j], acc[i][j], 0, 0, 0);
    }
  }
#pragma unroll
  for (int i = 0; i < 4; i++) {
    int r0 = (int)arow0 + waveM + i * 16 + quad * 4;
#pragma unroll
    for (int j = 0; j < 4; j++) {
      int cN = (int)brow0 + waveN + j * 16 + l16;
#pragma unroll
      for (int r = 0; r < 4; r++) {
        size_t idx = (size_t)(r0 + r) * N + cN;
        float vacc = acc[i][j][r];
        if (MODE == 0) {
          outh[idx] = f2bf(vacc);
        } else if (MODE == 1) {
          outf[idx] = vacc + res[idx];
        } else {
          float z = vacc + bias[cN];
          float ge = 0.5f * z * (1.f + erff(z * 0.70710678118654752f));
          outf[idx] = ge + res[idx];
        }
      }
    }
  }
}

// -------------------- causal conv(4) + SiLU + L2norm for q,k (bf16 out) --------------------
__global__ __launch_bounds__(256) void conv_qk_kernel(
    const u16* __restrict__ qkv, const float* __restrict__ cwq, const float* __restrict__ cwk,
    u16* __restrict__ qf, u16* __restrict__ kf) {
  __shared__ float sred[4];
  int row = blockIdx.x, tid = threadIdx.x;
  int t = row & 2047;
  int isK = (blockIdx.y >= 4);
  int hh = blockIdx.y & 3;
  int c = hh * 256 + tid;
  const float* cw = isK ? cwk : cwq;
  int col = (isK ? 1024 : 0) + c;
  float acc = 0.f;
#pragma unroll
  for (int i = 0; i < 4; i++) {
    int tt = t - 3 + i;
    if (tt >= 0) acc = fmaf(cw[c * 4 + i], bf2f(qkv[(size_t)(row - 3 + i) * 4096 + col]), acc);
  }
  float y = acc * sigmoidf_(acc);
  float ssq = blk_sum(y * y, sred, tid);
  float r = rsqrtf(ssq + 1e-6f);
  float outv = y * r * (isK ? 1.f : 0.0625f);
  (isK ? kf : qf)[(size_t)row * 1024 + c] = f2bf(outv);
}

// -------------------- causal conv(4) + SiLU for v (bf16 out) --------------------
__global__ __launch_bounds__(256) void conv_v_kernel(
    const u16* __restrict__ qkv, const float* __restrict__ cwv, u16* __restrict__ vf) {
  int row = blockIdx.x, tid = threadIdx.x;
  int t = row & 2047;
  int c0 = blockIdx.y * 1024 + tid * 4;
  float a0 = 0, a1 = 0, a2 = 0, a3 = 0;
#pragma unroll
  for (int i = 0; i < 4; i++) {
    int tt = t - 3 + i;
    if (tt >= 0) {
      uint2 raw = *(const uint2*)(qkv + (size_t)(row - 3 + i) * 4096 + 2048 + c0);
      a0 = fmaf(cwv[(c0 + 0) * 4 + i], bf2f(raw.x & 0xffffu), a0);
      a1 = fmaf(cwv[(c0 + 1) * 4 + i], bf2f(raw.x >> 16), a1);
      a2 = fmaf(cwv[(c0 + 2) * 4 + i], bf2f(raw.y & 0xffffu), a2);
      a3 = fmaf(cwv[(c0 + 3) * 4 + i], bf2f(raw.y >> 16), a3);
    }
  }
  a0 = a0 * sigmoidf_(a0);
  a1 = a1 * sigmoidf_(a1);
  a2 = a2 * sigmoidf_(a2);
  a3 = a3 * sigmoidf_(a3);
  uint2 pk;
  pk.x = pack2(a0, a1);
  pk.y = pack2(a2, a3);
  *(uint2*)(vf + (size_t)row * 2048 + c0) = pk;
}

// ==================== chunked gated delta rule ====================
// Chunk C=64. Per chunk, with G_i = cumsum(g) (inclusive), gamma_i = exp(G_i):
//   A_ij = exp(G_i-G_j) k_i.k_j (j<i);  M = (I + diag(b) A)^-1 diag(b)
//   delta = M (V - rowscale(gamma) K S0);  O_i = gamma_i (Q S0)_i + (B delta)_i,
//   B_ij = exp(G_i-G_j) q_i.k_j (j<=i);   S' = gamma_63 S0 + K^T rowscale(exp(G63-G_i)) delta
// All exp args <= 0 -> no overflow.

// -------- Phase A: per (b,h,chunk) block: emits M, B (bf16), KT (bf16), gamma pack --------
__global__ __launch_bounds__(256) void phaseA_kernel(
    const u16* __restrict__ kf, const u16* __restrict__ qf, const float2* __restrict__ gb2,
    u16* __restrict__ KTg, u16* __restrict__ Bg, u16* __restrict__ Mg,
    float2* __restrict__ gpk) {
  __shared__ uint8_t sm[51456];
  float* Nl  = (float*)sm;               // 64*66*4 = 16896
  float* gl  = (float*)(sm + 16896);     // 256
  float* bl  = (float*)(sm + 17152);     // 256
  float* GL  = (float*)(sm + 17408);     // 256
  u16*  Klds = (u16*)(sm + 17664);       // 64*264*2 = 33792
  float* Ml  = (float*)(sm + 17664);     // alias Klds (used after KT writeout)

  const int tid = threadIdx.x;
  const int lane = tid & 63;
  const int wv = tid >> 6;
  const int quad = lane >> 4;
  const int l16 = lane & 15;
  const int bh = blockIdx.x >> 5;        // 0..15
  const int ch = blockIdx.x & 31;        // 0..31
  const int b = bh >> 2, h = bh & 3;
  const int gr0 = b * 2048 + ch * 64;
  const size_t cid = (size_t)blockIdx.x; // == bh*32+ch ordering equivalent
  const size_t cid2 = (size_t)bh * 32 + ch;

  // A1: load g, beta
  if (tid < 64) {
    float2 gv = gb2[(size_t)(gr0 + tid) * 4 + h];
    gl[tid] = gv.x; bl[tid] = gv.y;
  }
  __syncthreads();
  // A2: inclusive prefix G
  if (tid < 64) {
    float s = 0.f;
    for (int j = 0; j < 64; j++) { if (j <= tid) s += gl[j]; }
    GL[tid] = s;
  }
  // A3: stage K chunk into LDS (for transpose writeout)
  {
    int r = tid >> 2, p = tid & 3;
    const u16* src = kf + (size_t)(gr0 + r) * 1024 + h * 256 + p * 64;
#pragma unroll
    for (int it = 0; it < 8; it++)
      *(uint4*)&Klds[r * 264 + p * 64 + it * 8] = *(const uint4*)(src + it * 8);
  }
  // A4/A5: P = K K^T, Qp = Q K^T (global frags)
  f32x4 ap[4], aq4[4];
#pragma unroll
  for (int nt = 0; nt < 4; nt++) { ap[nt] = (f32x4){0, 0, 0, 0}; aq4[nt] = (f32x4){0, 0, 0, 0}; }
  for (int ks = 0; ks < 8; ks++) {
    bfrag8 afk = *(const bfrag8*)(kf + (size_t)(gr0 + 16 * wv + l16) * 1024 + h * 256 + ks * 32 + quad * 8);
    bfrag8 afq = *(const bfrag8*)(qf + (size_t)(gr0 + 16 * wv + l16) * 1024 + h * 256 + ks * 32 + quad * 8);
#pragma unroll
    for (int nt = 0; nt < 4; nt++) {
      bfrag8 bfk = *(const bfrag8*)(kf + (size_t)(gr0 + 16 * nt + l16) * 1024 + h * 256 + ks * 32 + quad * 8);
      ap[nt]  = __builtin_amdgcn_mfma_f32_16x16x32_bf16(afk, bfk, ap[nt], 0, 0, 0);
      aq4[nt] = __builtin_amdgcn_mfma_f32_16x16x32_bf16(afq, bfk, aq4[nt], 0, 0, 0);
    }
  }
  __syncthreads();   // GL ready, Klds staged
  // A6: scale + mask; write N (LDS) and B (global); KT writeout; gamma pack
#pragma unroll
  for (int nt = 0; nt < 4; nt++) {
#pragma unroll
    for (int r = 0; r < 4; r++) {
      int i = 16 * wv + quad * 4 + r;
      int j = 16 * nt + l16;
      float e = __expf(GL[i] - GL[j]);
      Nl[i * 66 + j] = (j < i) ? bl[i] * e * ap[nt][r] : 0.f;
      float bvv = (j <= i) ? e * aq4[nt][r] : 0.f;
      Bg[cid2 * 4096 + i * 64 + j] = f2bf(bvv);
    }
  }
  for (int e = 0; e < 64; e++) {
    int idx = e * 256 + tid;
    int i2 = idx & 63, k2 = idx >> 6;
    KTg[cid2 * 16384 + (size_t)k2 * 64 + i2] = Klds[i2 * 264 + k2];
  }
  if (tid < 64) {
    float2 gp;
    gp.x = __expf(GL[tid]);
    gp.y = __expf(GL[63] - GL[tid]);
    gpk[cid2 * 64 + tid] = gp;
  }
  __syncthreads();   // N complete; KT writeout done (Ml aliases Klds)
  // A7: forward substitution M = (I+N)^-1 diag(b); column per lane (wave 0)
  if (tid < 64) {
    int c = tid;
    for (int i = 0; i < 64; i++) {
      float acc = (i == c) ? bl[i] : 0.f;
      for (int j = 0; j < i; j++) acc -= Nl[i * 66 + j] * Ml[j * 66 + c];
      Ml[i * 66 + c] = acc;
    }
  }
  __syncthreads();
  // A8: write M bf16
  for (int e = 0; e < 16; e++) {
    int idx = e * 256 + tid;
    int i2 = idx >> 6, j2 = idx & 63;
    Mg[cid2 * 4096 + i2 * 64 + j2] = f2bf(Ml[i2 * 66 + j2]);
  }
  (void)cid;
}

// -------- Phase B: per (b,h,v-slice32) block; sequential over 32 chunks --------
__global__ __launch_bounds__(256) void phaseB_kernel(
    const u16* __restrict__ kf, const u16* __restrict__ qf, const u16* __restrict__ vf,
    const u16* __restrict__ KTg, const u16* __restrict__ Bg, const u16* __restrict__ Mg,
    const float2* __restrict__ gpk, u16* __restrict__ obuf) {
  __shared__ u16 S0T[32 * 264];   // S0^T [n][k], padded
  __shared__ u16 rhsT[32 * 72];
  __shared__ u16 dT[32 * 72];
  __shared__ u16 dhT[32 * 72];
  __shared__ float gin_s[64], gout_s[64];

  const int tid = threadIdx.x;
  const int lane = tid & 63;
  const int wv = tid >> 6;
  const int quad = lane >> 4;
  const int l16 = lane & 15;
  const int bh = blockIdx.x >> 4;   // 0..15
  const int sl = blockIdx.x & 15;   // v-slice of 32
  const int b = bh >> 2, h = bh & 3;

  f32x4 S[8];                       // k-tile(4) x n-tile(2); wave wv owns k in [64*wv, 64*wv+64)
#pragma unroll
  for (int t = 0; t < 8; t++) S[t] = (f32x4){0, 0, 0, 0};

  for (int ch = 0; ch < 32; ch++) {
    const size_t cid = (size_t)bh * 32 + ch;
    const int gr0 = b * 2048 + ch * 64;
    const u16* kfc = kf + (size_t)gr0 * 1024 + h * 256;
    const u16* qfc = qf + (size_t)gr0 * 1024 + h * 256;
    const u16* vfc = vf + (size_t)gr0 * 2048 + h * 512 + sl * 32;
    u16* oc = obuf + (size_t)gr0 * 2048 + h * 512 + sl * 32;
    const u16* KTc = KTg + cid * 16384;
    const u16* Mc  = Mg + cid * 4096;
    const u16* Bc  = Bg + cid * 4096;

    // step 1: stage gammas + S0^T (bf16)
    if (tid < 64) {
      float2 gp = gpk[cid * 64 + tid];
      gin_s[tid] = gp.x; gout_s[tid] = gp.y;
    }
#pragma unroll
    for (int kt = 0; kt < 4; kt++)
#pragma unroll
      for (int nt = 0; nt < 2; nt++) {
        int k = wv * 64 + kt * 16 + quad * 4;
        int n = nt * 16 + l16;
        f32x4 sv = S[kt * 2 + nt];
        uint2 pk;
        pk.x = pack2(sv[0], sv[1]);
        pk.y = pack2(sv[2], sv[3]);
        *(uint2*)&S0T[n * 264 + k] = pk;
      }
    __syncthreads();

    // step 2: rhs = V - rowscale(gin) * (K @ S0)
    f32x4 ar[2] = {(f32x4){0, 0, 0, 0}, (f32x4){0, 0, 0, 0}};
    for (int ks = 0; ks < 8; ks++) {
      bfrag8 af = *(const bfrag8*)(kfc + (size_t)(16 * wv + l16) * 1024 + ks * 32 + quad * 8);
#pragma unroll
      for (int nt = 0; nt < 2; nt++) {
        bfrag8 bf = *(const bfrag8*)&S0T[(nt * 16 + l16) * 264 + ks * 32 + quad * 8];
        ar[nt] = __builtin_amdgcn_mfma_f32_16x16x32_bf16(af, bf, ar[nt], 0, 0, 0);
      }
    }
#pragma unroll
    for (int nt = 0; nt < 2; nt++) {
      float rv[4];
#pragma unroll
      for (int r = 0; r < 4; r++) {
        int i = 16 * wv + quad * 4 + r;
        float vvv = bf2f(vfc[(size_t)i * 2048 + nt * 16 + l16]);
        rv[r] = vvv - gin_s[i] * ar[nt][r];
      }
      uint2 pk;
      pk.x = pack2(rv[0], rv[1]);
      pk.y = pack2(rv[2], rv[3]);
      *(uint2*)&rhsT[(nt * 16 + l16) * 72 + 16 * wv + quad * 4] = pk;
    }
    __syncthreads();

    // step 3: delta = M @ rhs; write dT (raw) and dhT (rowscale gout)
    f32x4 ad[2] = {(f32x4){0, 0, 0, 0}, (f32x4){0, 0, 0, 0}};
    for (int ks = 0; ks < 2; ks++) {
      bfrag8 af = *(const bfrag8*)(Mc + (size_t)(16 * wv + l16) * 64 + ks * 32 + quad * 8);
#pragma unroll
      for (int nt = 0; nt < 2; nt++) {
        bfrag8 bf = *(const bfrag8*)&rhsT[(nt * 16 + l16) * 72 + ks * 32 + quad * 8];
        ad[nt] = __builtin_amdgcn_mfma_f32_16x16x32_bf16(af, bf, ad[nt], 0, 0, 0);
      }
    }
#pragma unroll
    for (int nt = 0; nt < 2; nt++) {
      int i0 = 16 * wv + quad * 4;
      uint2 pk;
      pk.x = pack2(ad[nt][0], ad[nt][1]);
      pk.y = pack2(ad[nt][2], ad[nt][3]);
      *(uint2*)&dT[(nt * 16 + l16) * 72 + i0] = pk;
      uint2 pk2;
      pk2.x = pack2(gout_s[i0] * ad[nt][0], gout_s[i0 + 1] * ad[nt][1]);
      pk2.y = pack2(gout_s[i0 + 2] * ad[nt][2], gout_s[i0 + 3] * ad[nt][3]);
      *(uint2*)&dhT[(nt * 16 + l16) * 72 + i0] = pk2;
    }
    __syncthreads();

    // step 4: O = rowscale(gin) * (Q @ S0) + B @ delta
    f32x4 ao[2] = {(f32x4){0, 0, 0, 0}, (f32x4){0, 0, 0, 0}};
    for (int ks = 0; ks < 2; ks++) {
      bfrag8 af = *(const bfrag8*)(Bc + (size_t)(16 * wv + l16) * 64 + ks * 32 + quad * 8);
#pragma unroll
      for (int nt = 0; nt < 2; nt++) {
        bfrag8 bf = *(const bfrag8*)&dT[(nt * 16 + l16) * 72 + ks * 32 + quad * 8];
        ao[nt] = __builtin_amdgcn_mfma_f32_16x16x32_bf16(af, bf, ao[nt], 0, 0, 0);
      }
    }
    f32x4 aq[2] = {(f32x4){0, 0, 0, 0}, (f32x4){0, 0, 0, 0}};
    for (int ks = 0; ks < 8; ks++) {
      bfrag8 af = *(const bfrag8*)(qfc + (size_t)(16 * wv + l16) * 1024 + ks * 32 + quad * 8);
#pragma unroll
      for (int nt = 0; nt < 2; nt++) {
        bfrag8 bf = *(const bfrag8*)&S0T[(nt * 16 + l16) * 264 + ks * 32 + quad * 8];
        aq[nt] = __builtin_amdgcn_mfma_f32_16x16x32_bf16(af, bf, aq[nt], 0, 0, 0);
      }
    }
#pragma unroll
    for (int nt = 0; nt < 2; nt++)
#pragma unroll
      for (int r = 0; r < 4; r++) {
        int i = 16 * wv + quad * 4 + r;
        float ov = gin_s[i] * aq[nt][r] + ao[nt][r];
        oc[(size_t)i * 2048 + nt * 16 + l16] = f2bf(ov);
      }

    // step 5: S = gammaC * S + KT @ dhat
    float gC = gin_s[63];
#pragma unroll
    for (int kt = 0; kt < 4; kt++) {
      f32x4 c0 = S[kt * 2] * gC;
      f32x4 c1 = S[kt * 2 + 1] * gC;
      for (int ks = 0; ks < 2; ks++) {
        bfrag8 af = *(const bfrag8*)(KTc + (size_t)(wv * 64 + kt * 16 + l16) * 64 + ks * 32 + quad * 8);
        bfrag8 bf0 = *(const bfrag8*)&dhT[(0 * 16 + l16) * 72 + ks * 32 + quad * 8];
        bfrag8 bf1 = *(const bfrag8*)&dhT[(1 * 16 + l16) * 72 + ks * 32 + quad * 8];
        c0 = __builtin_amdgcn_mfma_f32_16x16x32_bf16(af, bf0, c0, 0, 0, 0);
        c1 = __builtin_amdgcn_mfma_f32_16x16x32_bf16(af, bf1, c1, 0, 0, 0);
      }
      S[kt * 2] = c0;
      S[kt * 2 + 1] = c1;
    }
    __syncthreads();   // protect S0T/rhsT/dT for next chunk
  }
}

// -------------------- gated RMS-norm of o: bf16 out --------------------
__global__ __launch_bounds__(256) void onorm_kernel(
    const u16* __restrict__ o, const u16* __restrict__ gate,
    const float* __restrict__ onw, u16* __restrict__ ofin) {
  __shared__ float sred[4];
  int row = blockIdx.x, hh = blockIdx.y, tid = threadIdx.x;
  size_t base = (size_t)row * 2048 + hh * 512;
  uint32_t oraw = *(const uint32_t*)(o + base + tid * 2);
  float o0 = bf2f(oraw & 0xffffu), o1 = bf2f(oraw >> 16);
  float ssq = blk_sum(o0 * o0 + o1 * o1, sred, tid);
  float rinv = rsqrtf(ssq * (1.f / 512.f) + 1e-6f);
  uint32_t graw = *(const uint32_t*)(gate + base + tid * 2);
  float g0 = bf2f(graw & 0xffffu), g1 = bf2f(graw >> 16);
  float r0 = o0 * rinv * onw[tid * 2 + 0] * (g0 * sigmoidf_(g0));
  float r1 = o1 * rinv * onw[tid * 2 + 1] * (g1 * sigmoidf_(g1));
  *(uint32_t*)(ofin + base + tid * 2) = pack2(r0, r1);
}

// -------------------- LN2 --------------------
__global__ __launch_bounds__(256) void ln2_kernel(
    const float* __restrict__ x1, const float* __restrict__ g2, const float* __restrict__ b2,
    u16* __restrict__ h2) {
  __shared__ float sred[4];
  int row = blockIdx.x, tid = threadIdx.x;
  const float4 xv = ((const float4*)(x1 + (size_t)row * 1024))[tid];
  float ts  = blk_sum(xv.x + xv.y + xv.z + xv.w, sred, tid);
  float ts2 = blk_sum(xv.x * xv.x + xv.y * xv.y + xv.z * xv.z + xv.w * xv.w, sred, tid);
  float mean = ts * (1.f / 1024.f);
  float inv = rsqrtf(ts2 * (1.f / 1024.f) - mean * mean + 1e-5f);
  int c = tid * 4;
  float h0 = (xv.x - mean) * inv * g2[c + 0] + b2[c + 0];
  float h1 = (xv.y - mean) * inv * g2[c + 1] + b2[c + 1];
  float h2v = (xv.z - mean) * inv * g2[c + 2] + b2[c + 2];
  float h3 = (xv.w - mean) * inv * g2[c + 3] + b2[c + 3];
  uint2 pk;
  pk.x = pack2(h0, h1);
  pk.y = pack2(h2v, h3);
  *(uint2*)(h2 + (size_t)row * 1024 + c) = pk;
}

// ==================== launch ====================
// Workspace (MB): [0,64) qkvp -> (obuf[0,32), PA outputs [32,56.3) -> gate[32,64));
// [64,80) hbf; [80,98) weight transposes; [98,162) qf/kf/vf -> (ofin, h2bf); [162,+) gb2.
extern "C" void kernel_launch(void* const* d_in, const int* in_sizes, int n_in,
                              void* d_out, int out_size, void* d_ws, size_t ws_size,
                              hipStream_t stream) {
  (void)in_sizes; (void)n_in; (void)out_size; (void)ws_size;
  const float* x    = (const float*)d_in[0];
  const float* ln1g = (const float*)d_in[1];
  const float* ln1b = (const float*)d_in[2];
  const float* ln2g = (const float*)d_in[3];
  const float* ln2b = (const float*)d_in[4];
  const float* rmsw = (const float*)d_in[5];
  const float* Wq   = (const float*)d_in[6];
  const float* Wk   = (const float*)d_in[7];
  const float* Wv   = (const float*)d_in[8];
  const float* cwq  = (const float*)d_in[9];
  const float* cwk  = (const float*)d_in[10];
  const float* cwv  = (const float*)d_in[11];
  const float* Wa   = (const float*)d_in[12];
  const float* dtb  = (const float*)d_in[13];
  const float* Alog = (const float*)d_in[14];
  const float* Wb   = (const float*)d_in[15];
  const float* Wg   = (const float*)d_in[16];
  const float* onw  = (const float*)d_in[17];
  const float* Wo   = (const float*)d_in[18];
  const float* W2   = (const float*)d_in[19];
  const float* b2   = (const float*)d_in[20];

  uint8_t* ws = (uint8_t*)d_ws;
  const size_t MB = 1024ull * 1024;
  u16*   qkvp  = (u16*)(ws);               // 64MB
  u16*   obuf  = (u16*)(ws);               // 32MB (overlay)
  u16*   KTg   = (u16*)(ws + 32 * MB);     // 16MB  (PhaseA out, dead before gate write)
  u16*   Bg    = (u16*)(ws + 48 * MB);     // 4MB
  u16*   Mg    = (u16*)(ws + 52 * MB);     // 4MB
  float2* gpk  = (float2*)(ws + 56 * MB);  // 256KB
  u16*   gate  = (u16*)(ws + 32 * MB);     // 32MB (overlay, written after PhaseB)
  u16*   hbf   = (u16*)(ws + 64 * MB);     // 16MB
  u16*   WTqkv = (u16*)(ws + 80 * MB);     // 8MB
  u16*   WgT   = (u16*)(ws + 88 * MB);     // 4MB
  u16*   WoT   = (u16*)(ws + 92 * MB);     // 4MB
  u16*   W2T   = (u16*)(ws + 96 * MB);     // 2MB
  u16*   qf    = (u16*)(ws + 98 * MB);     // 16MB
  u16*   kf    = (u16*)(ws + 114 * MB);    // 16MB
  u16*   vf    = (u16*)(ws + 130 * MB);    // 32MB
  u16*   ofin  = (u16*)(ws + 98 * MB);     // 32MB (overlay qf/kf)
  u16*   h2bf  = (u16*)(ws + 130 * MB);    // 16MB (overlay vf)
  float2* gb2  = (float2*)(ws + 162 * MB); // 256KB
  float* x1    = (float*)d_out;
  float* outp  = (float*)d_out;

  dim3 tb(32, 8);
  transpose_w<<<dim3(32, 32), tb, 0, stream>>>(Wq, WTqkv,               1024, 1024);
  transpose_w<<<dim3(32, 32), tb, 0, stream>>>(Wk, WTqkv + 1024 * 1024, 1024, 1024);
  transpose_w<<<dim3(64, 32), tb, 0, stream>>>(Wv, WTqkv + 2048 * 1024, 1024, 2048);
  transpose_w<<<dim3(64, 32), tb, 0, stream>>>(Wg, WgT,                 1024, 2048);
  transpose_w<<<dim3(32, 64), tb, 0, stream>>>(Wo, WoT,                 2048, 1024);
  transpose_w<<<dim3(32, 32), tb, 0, stream>>>(W2, W2T,                 1024, 1024);

  k1_kernel<<<8192, 256, 0, stream>>>(x, ln1g, ln1b, rmsw, Wa, Wb, dtb, Alog, hbf, gb2);
  gemm_bt<0><<<dim3(32, 64), 256, 0, stream>>>(hbf, WTqkv, 8192, 4096, 1024, nullptr, qkvp, nullptr, nullptr);
  conv_qk_kernel<<<dim3(8192, 8), 256, 0, stream>>>(qkvp, cwq, cwk, qf, kf);
  conv_v_kernel<<<dim3(8192, 2), 256, 0, stream>>>(qkvp, cwv, vf);
  phaseA_kernel<<<512, 256, 0, stream>>>(kf, qf, gb2, KTg, Bg, Mg, gpk);
  phaseB_kernel<<<256, 256, 0, stream>>>(kf, qf, vf, KTg, Bg, Mg, gpk, obuf);
  gemm_bt<0><<<dim3(16, 64), 256, 0, stream>>>(hbf, WgT, 8192, 2048, 1024, nullptr, gate, nullptr, nullptr);
  onorm_kernel<<<dim3(8192, 4), 256, 0, stream>>>(obuf, gate, onw, ofin);
  gemm_bt<1><<<dim3(8, 64), 256, 0, stream>>>(ofin, WoT, 8192, 1024, 2048, x1, nullptr, x, nullptr);
  ln2_kernel<<<8192, 256, 0, stream>>>(x1, ln2g, ln2b, h2bf);
  gemm_bt<2><<<dim3(8, 64), 256, 0, stream>>>(h2bf, W2T, 8192, 1024, 1024, outp, nullptr, x1, b2);
}